// Round 14
// baseline (531.370 us; speedup 1.0000x reference)
//
#include <hip/hip_runtime.h>
#include <hip/hip_bf16.h>
#include <math.h>

#define T_   2048
#define B_   2
#define E_   1024
#define H_   16
#define D_   64
#define NH_  32
#define M_   4096

typedef __attribute__((ext_vector_type(8))) short s8b;   // 8 bf16 (4 VGPRs)
typedef __attribute__((ext_vector_type(4))) float f4;    // 4 f32 acc
typedef __attribute__((ext_vector_type(16))) float f16v; // 32x32 MFMA acc

#define MFMA_B16(a,b,c) __builtin_amdgcn_mfma_f32_16x16x32_bf16(a,b,c,0,0,0)
#define MFMA32(a,b,c)   __builtin_amdgcn_mfma_f32_32x32x16_bf16(a,b,c,0,0,0)
#define LOG2E 1.44269504088896f

__device__ __forceinline__ unsigned short f2bu(float f) {
    union { __hip_bfloat16 h; unsigned short u; } cv;
    cv.h = __float2bfloat16(f);
    return cv.u;
}
// fast bf16: round-half-up truncation (positive finite values) — 2 VALU ops
__device__ __forceinline__ unsigned short f2bu_fast(float f) {
    return (unsigned short)((__float_as_uint(f) + 0x8000u) >> 16);
}
__device__ __forceinline__ float bu2f(unsigned short u) {
    union { __hip_bfloat16 h; unsigned short u; } cv; cv.u = u;
    return __bfloat162float(cv.h);
}
__device__ __forceinline__ unsigned int pk2(float a, float b) {
    return (unsigned int)f2bu(a) | ((unsigned int)f2bu(b) << 16);
}
// pack two f32 -> packed bf16 pair with round-half-up (cheap)
__device__ __forceinline__ unsigned int pk2_fast(float a, float b) {
    return ((__float_as_uint(a) + 0x8000u) >> 16) |
           ((__float_as_uint(b) + 0x8000u) & 0xFFFF0000u);
}
// raw v_exp_f32 — exp2f() without fast-math expands to a denorm-guard
// sequence (~12 extra VALU ops); attention scores never reach denormals.
__device__ __forceinline__ float fexp2(float x) {
    return __builtin_amdgcn_exp2f(x);
}
__device__ __forceinline__ float ld1d(const void* p, size_t idx, bool f32) {
    return f32 ? ((const float*)p)[idx] : bu2f(((const unsigned short*)p)[idx]);
}
// swap: a' = {a.lo32, b.lo32}, b' = {a.hi32, b.hi32} (v_permlane32_swap_b32)
__device__ __forceinline__ void plswap(unsigned int &a, unsigned int &b) {
    auto r = __builtin_amdgcn_permlane32_swap(a, b, false, false);
    a = r[0]; b = r[1];
}
// async global->LDS, 16 B per lane (GEMMs only — attn uses register prefetch
// because its per-tile barrier drains vmcnt(0) and exposes the DMA latency)
__device__ __forceinline__ void glds16(const unsigned short* g, unsigned short* l) {
    __builtin_amdgcn_global_load_lds(
        (const __attribute__((address_space(1))) unsigned int*)g,
        (__attribute__((address_space(3))) unsigned int*)l, 16, 0, 0);
}
// dtype detect, wave-local (identical result in every wave): sample 64 u16
// words of x; bf16 data -> ~all exponent fields sane; f32-as-u16 -> ~half.
__device__ __forceinline__ bool detect_f32(const unsigned short* q16) {
    int e = (q16[threadIdx.x & 63] >> 7) & 0xFF;
    bool sane = (e == 0) || (e >= 97 && e <= 157);
    unsigned long long m = __ballot(sane);
    return __popcll(m) < 56;   // true = f32 inputs
}

// ---------------------------------------------------------------------------
// One-pass f32->bf16 conversion of x, Wq..Wo, bq..bo into ws. R21: exact 1D
// grid (4100 blocks). Also publishes the dtype flag.
// ---------------------------------------------------------------------------
__global__ __launch_bounds__(256) void cvt_bf16(
    const void* __restrict__ x,
    const void* __restrict__ Wq, const void* __restrict__ Wk,
    const void* __restrict__ Wv, const void* __restrict__ Wo,
    const void* __restrict__ bq, const void* __restrict__ bk,
    const void* __restrict__ bv, const void* __restrict__ bo,
    unsigned short* __restrict__ xw, unsigned short* __restrict__ Ww,
    unsigned short* __restrict__ bw, int* __restrict__ flag)
{
    const bool f32m = detect_f32((const unsigned short*)x);
    const int bid = blockIdx.x;
    if (bid == 0 && threadIdx.x == 0)
        *flag = f32m ? 1 : 0;
    int y, lb;
    if (bid < 2048)       { y = 0;                      lb = bid; }
    else if (bid < 4096)  { y = 1 + ((bid - 2048) >> 9); lb = (bid - 2048) & 511; }
    else                  { y = 5 + (bid - 4096);        lb = 0; }
    const void* src; unsigned short* dst; int n;
    if (y == 0)      { src = x; dst = xw; n = M_ * E_; }
    else if (y <= 4) {
        src = (y == 1) ? Wq : (y == 2) ? Wk : (y == 3) ? Wv : Wo;
        dst = Ww + (size_t)(y - 1) * E_ * E_; n = E_ * E_;
    } else {
        src = (y == 5) ? bq : (y == 6) ? bk : (y == 7) ? bv : bo;
        dst = bw + (size_t)(y - 5) * E_; n = E_;
    }
    int i = (lb * 256 + threadIdx.x) * 8;
    if (i >= n) return;
    if (f32m) {
        const float* s = (const float*)src + i;
        float4 f0 = *(const float4*)s, f1 = *(const float4*)(s + 4);
        union { unsigned int d[4]; s8b v; } u;
        u.d[0] = pk2(f0.x, f0.y); u.d[1] = pk2(f0.z, f0.w);
        u.d[2] = pk2(f1.x, f1.y); u.d[3] = pk2(f1.z, f1.w);
        *(s8b*)(dst + i) = u.v;
    } else {
        *(s8b*)(dst + i) = *(const s8b*)((const unsigned short*)src + i);
    }
}

// ---------------------------------------------------------------------------
// QKV projection, bf16 MFMA GEMM, XCD swizzle, glds staging (xor-swizzled),
// double-buffered single-barrier. p==2 (V) written TRANSPOSED [N][D][T] via
// LDS-staged coalesced stores (R20). R21: Q/K epilogue ALSO LDS-staged.
// ---------------------------------------------------------------------------
__global__ __launch_bounds__(256, 3) void qkv_gemm(
    const unsigned short* __restrict__ xw, const unsigned short* __restrict__ Ww,
    const unsigned short* __restrict__ bw,
    unsigned short* __restrict__ qo, unsigned short* __restrict__ ko,
    unsigned short* __restrict__ vo)
{
    const int bid = blockIdx.x;            // 768 blocks
    const int r_ = bid & 7, s_ = bid >> 3;
    const int g = r_ + 8 * (s_ >> 3);      // group in [0,96): (m,p)
    const int e0 = (s_ & 7) * 128;
    const int m0 = (g & 31) * 128;
    const int p  = g >> 5;
    const unsigned short* W    = Ww + (size_t)p * E_ * E_;
    const unsigned short* bias = bw + (size_t)p * E_;
    const float scale = (p == 0) ? 0.125f * LOG2E : 1.0f;

    const int tid = threadIdx.x, w = tid >> 6, lane = tid & 63;
    const int quad = lane >> 4, lc = lane & 15;
    const int wx = w & 1, wy = w >> 1;

    __shared__ unsigned short smem[4][128 * 32];

    f4 acc[4][4];
    #pragma unroll
    for (int i = 0; i < 4; i++)
        #pragma unroll
        for (int j = 0; j < 4; j++) acc[i][j] = (f4){0.f, 0.f, 0.f, 0.f};

    const int gr = lane >> 2;
    const int gc = (lane & 3) ^ ((lane >> 2) & 3);
    const size_t aoff = (size_t)(m0 + w*32 + gr) * E_ + gc*8;
    const size_t boff = (size_t)(e0 + w*32 + gr) * E_ + gc*8;

    #pragma unroll
    for (int j = 0; j < 2; j++) {
        glds16(xw + aoff + (size_t)j*16*E_, &smem[0][(w*128 + j*64) * 8]);
        glds16(W  + boff + (size_t)j*16*E_, &smem[2][(w*128 + j*64) * 8]);
    }
    __syncthreads();

    const int fcA = quad ^ (lc & 3);
    for (int k0 = 0; k0 < E_; k0 += 32) {
        const int cur = (k0 >> 5) & 1;
        if (k0 + 32 < E_) {
            #pragma unroll
            for (int j = 0; j < 2; j++) {
                glds16(xw + aoff + (size_t)j*16*E_ + k0 + 32, &smem[cur^1][(w*128 + j*64) * 8]);
                glds16(W  + boff + (size_t)j*16*E_ + k0 + 32, &smem[2 + (cur^1)][(w*128 + j*64) * 8]);
            }
        }
        s8b af[4], bfr[4];
        #pragma unroll
        for (int i = 0; i < 4; i++)
            af[i]  = *(const s8b*)&smem[cur][((wy*64 + i*16 + lc)*4 + fcA) * 8];
        #pragma unroll
        for (int i = 0; i < 4; i++)
            bfr[i] = *(const s8b*)&smem[2 + cur][((wx*64 + i*16 + lc)*4 + fcA) * 8];
        #pragma unroll
        for (int ms = 0; ms < 4; ms++)
            #pragma unroll
            for (int ns = 0; ns < 4; ns++)
                acc[ms][ns] = MFMA_B16(af[ms], bfr[ns], acc[ms][ns]);
        __syncthreads();
    }

    float bias_v[4];
    #pragma unroll
    for (int ns = 0; ns < 4; ns++) bias_v[ns] = bu2f(bias[e0 + wx*64 + ns*16 + lc]);

    unsigned int* cst = (unsigned int*)&smem[0][0];   // 8192 u32 = 32 KB
    if (p < 2) {
        // ---- Q/K epilogue, LDS-staged ----
        #pragma unroll
        for (int ms = 0; ms < 4; ms++)
            #pragma unroll
            for (int ns = 0; ns < 4; ns++)
                #pragma unroll
                for (int r2 = 0; r2 < 4; r2++) {
                    float val = (acc[ms][ns][r2] + bias_v[ns]) * scale;
                    float nb = __shfl_xor(val, 1);
                    if (!(lane & 1)) {
                        int mi = wy*64 + ms*16 + quad*4 + r2;     // 0..127
                        int ei = wx*64 + ns*16 + lc;              // 0..127, even
                        int row = ((mi & 1) * 2 + (ei >> 6)) * 64 + (mi >> 1);
                        int col = (ei & 63) >> 1;                 // 0..31
                        cst[row*32 + (col ^ ((row & 7) << 2))] = pk2(val, nb);
                    }
                }
        __syncthreads();
        unsigned int* dst32 = (unsigned int*)((p == 0) ? qo : ko);
        #pragma unroll
        for (int i = 0; i < 8; i++) {
            const int li  = i*256 + tid;              // 0..2047
            const int row = li >> 3;                  // 0..255
            const int ch  = li & 7;                   // 16B chunk
            uint4 vd = *(const uint4*)&cst[row*32 + ((ch*4) ^ ((row & 7) << 2))];
            const int bb = row >> 7, hh = (row >> 6) & 1, tq = row & 63;
            const size_t du = (((size_t)(bb*H_ + (e0 >> 6) + hh) * T_
                                + (m0 >> 1) + tq) << 5) + ch*4;
            *(uint4*)&dst32[du] = vd;
        }
    } else {
        // ---- V epilogue, LDS-staged (R20) ----
        #pragma unroll
        for (int ms = 0; ms < 4; ms++) {
            const int tq = wy*16 + ms*4 + quad;           // [0,32)
            #pragma unroll
            for (int ns = 0; ns < 4; ns++) {
                const int e_l = wx*64 + ns*16 + lc;       // [0,128)
                const int x = (e_l & 7) << 2;
                float v0 = acc[ms][ns][0] + bias_v[ns];
                float v1 = acc[ms][ns][1] + bias_v[ns];
                float v2 = acc[ms][ns][2] + bias_v[ns];
                float v3 = acc[ms][ns][3] + bias_v[ns];
                cst[e_l*64 + ( tq       ^ x)] = pk2(v0, v2);   // bb = 0
                cst[e_l*64 + ((32 + tq) ^ x)] = pk2(v1, v3);   // bb = 1
            }
        }
        __syncthreads();
        #pragma unroll
        for (int i = 0; i < 8; i++) {
            const int li  = i*256 + tid;                  // [0,2048)
            const int e_l = li >> 4;
            const int bb  = (li >> 3) & 1;
            const int ch  = li & 7;                       // 16B chunk
            const int x   = (e_l & 7) << 2;
            uint4 vd = *(const uint4*)&cst[e_l*64 + ((bb*32 + ch*4) ^ x)];
            const int e = e0 + e_l, h = e >> 6, d = e & 63;
            const size_t du = ((size_t)(bb*H_ + h) * 64 + d) * (T_/2)
                              + (m0 >> 2) + ch*4;
            *(uint4*)((unsigned int*)vo + du) = vd;
        }
    }
}

// ---------------------------------------------------------------------------
// Flash attention with Shaw bias — R24: R23 (32x32 MFMA, in-register P via
// permlane32_swap) + two VALU/store cuts now that VALUBusy (52%) is the top
// pipe: (1) rowsums via ones-MFMA32 into 3 class accumulators (replaces 15
// VALU adds + branches per tile; C/D col=lane&31=t, all rows equal, so
// ls[0] is this lane's t-sum — no cross-lane combine); (2) aout stores
// LDS-staged through dead v_s (R20 pattern, 3rd application) — old path
// scattered 8B per lane at 4KB stride.
// ---------------------------------------------------------------------------
__global__ __launch_bounds__(512, 4) void attn_mfma(
    const unsigned short* __restrict__ q, const unsigned short* __restrict__ k,
    const unsigned short* __restrict__ v,
    const void* __restrict__ rk_t, const void* __restrict__ rv_t,
    unsigned short* __restrict__ aout, const int* __restrict__ flag)
{
    const bool f32m = (*flag != 0);
    const int bid = blockIdx.x;
    const int n = bid & 31, qt = bid >> 5;
    const int t0 = qt * 128;
    const int tid = threadIdx.x, w = tid >> 6, lane = tid & 63;
    const int quad = lane >> 4, lc = lane & 15;
    const int tg = w >> 1, sh = w & 1;          // t-group, s-half
    const int lh = lane >> 5, tloc = lane & 31; // half-wave, local t (or row)
    const int t_bl = tg * 32 + tloc;            // block-local t of this lane

    __shared__ unsigned short k_s[2][64 * 64];   // K[s][d] swizzled; epi: O-buf/rv^T
    __shared__ unsigned short v_s[2][64 * 64];   // V^T[d][s] swizzled; epi: O-buf/out
    __shared__ unsigned short p_s[4][32 * 72];   // rk staging / P_extra per t-group
    __shared__ unsigned short qrk_s[128 * 36];   // qrk[t_local][r] bf16 (log2 dom.)
    __shared__ unsigned short diag16[128 * 33];  // e-values at |rel|<16, bf16
    __shared__ float st3[2][3][128];             // per-s-half {l, L, R} per t

    const unsigned short* qn = q + ((size_t)n * T_ + t0) * D_;
    const unsigned short* kn = k + (size_t)n * T_ * D_;
    const unsigned short* vn = v + (size_t)n * D_ * T_;   // V^T [D][T]

    for (int i = tid; i < 128 * 33; i += 512) diag16[i] = 0;

    // stage rk (bf16, padded [48][72], rows>=33 zero) into p_s area
    unsigned int* rks = (unsigned int*)&p_s[0][0];
    for (int i = tid; i < 48 * 36; i += 512) {
        int r = i / 36, c2 = i % 36;
        unsigned int val = 0;
        if (r < 33 && c2 < 32)
            val = pk2(ld1d(rk_t, r*64 + 2*c2, f32m), ld1d(rk_t, r*64 + 2*c2 + 1, f32m));
        rks[i] = val;
    }
    __syncthreads();

    // qrk[t][r] = q[t] . rk[r] via 16x16 MFMA (prologue-only, rows w*16..+15)
    {
        s8b qa16[2];
        #pragma unroll
        for (int kf = 0; kf < 2; kf++)
            qa16[kf] = *(const s8b*)(qn + (size_t)(w*16 + lc) * D_ + kf*32 + quad*8);
        for (int nt = 0; nt < 3; nt++) {
            s8b b0 = *(const s8b*)((const unsigned short*)rks + (nt*16 + lc)*72 + quad*8);
            s8b b1 = *(const s8b*)((const unsigned short*)rks + (nt*16 + lc)*72 + 32 + quad*8);
            f4 a = (f4){0.f, 0.f, 0.f, 0.f};
            a = MFMA_B16(qa16[0], b0, a);
            a = MFMA_B16(qa16[1], b1, a);
            #pragma unroll
            for (int r = 0; r < 4; r++) {
                float nb = __shfl_xor(a[r], 1);
                int col = nt*16 + lc;
                if (!(lane & 1) && col < 34)
                    ((unsigned int*)qrk_s)[(w*16 + quad*4 + r)*18 + (col >> 1)] = pk2(a[r], nb);
            }
        }
    }
    __syncthreads();   // rk staging (aliased with p_s) free after this

    // Q fragments, 32x32 B-operand: B[n=t=lane&31][k=d=16*ks+8*lh+j]
    s8b qa32[4];
    #pragma unroll
    for (int ks = 0; ks < 4; ks++)
        qa32[ks] = *(const s8b*)(qn + (size_t)t_bl * D_ + ks*16 + lh*8);

    const float qLn = bu2f(qrk_s[t_bl*36 + 0]);
    const float qRn = bu2f(qrk_s[t_bl*36 + 32]);
    float L_p = 0.f, R_p = 0.f;
    f16v O[2], lsNa, lsLa, lsRa;
    #pragma unroll
    for (int r = 0; r < 16; r++) { lsNa[r] = 0.f; lsLa[r] = 0.f; lsRa[r] = 0.f; }
    #pragma unroll
    for (int dt = 0; dt < 2; dt++)
        #pragma unroll
        for (int r = 0; r < 16; r++) O[dt][r] = 0.f;
    const short ob = (short)0x3F80;   // bf16 1.0
    const s8b ones = { ob, ob, ob, ob, ob, ob, ob, ob };

    // staging: row = w*8 + (lane>>3); phys chunk = lane&7; source chunk
    // gcc = phys ^ (row&7) ^ ((row>>3)&1)  [row&7 = lane>>3, row>>3 = w]
    const int grr = lane >> 3;
    const int gcc = (lane & 7) ^ grr ^ (w & 1);
    const size_t koff = (size_t)(w*8 + grr) * D_ + gcc*8;   // + s0*D_
    const size_t voff = (size_t)(w*8 + grr) * T_ + gcc*8;   // + s0

    // tile-order stagger: co-resident pair (bid, bid+256) -> opposite phase
    const int kts = ((bid >> 8) & 1) * 16;

    s8b kr0 = *(const s8b*)(kn + koff + (size_t)(kts * 64) * D_);
    s8b vr0 = *(const s8b*)(vn + voff + kts * 64);
    *(s8b*)&k_s[0][(w*64 + lane) * 8] = kr0;
    *(s8b*)&v_s[0][(w*64 + lane) * 8] = vr0;
    __syncthreads();

    const int rK   = sh*32 + tloc;                       // K row in k_s
    const int swzK = (rK & 7) ^ ((rK >> 3) & 1);
    for (int it = 0; it < 32; it++) {
        const int kt = (it + kts) & 31;
        const int s0 = kt * 64;
        const int cur = it & 1;
        if (it + 1 < 32) {
            const int s0n = ((it + 1 + kts) & 31) * 64;
            kr0 = *(const s8b*)(kn + koff + (size_t)s0n * D_);
            vr0 = *(const s8b*)(vn + voff + s0n);
        }

        const bool farL  = (s0 + 63 < t0 - 16);
        const bool farR  = (s0 > t0 + 143);
        const bool nearT = !farL && !farR;

        // K fragments, A-operand: A[m=s=rK][k=d=16*ks+8*lh+j]
        s8b ak32[4];
        #pragma unroll
        for (int ks = 0; ks < 4; ks++)
            ak32[ks] = *(const s8b*)&k_s[cur][(rK*8 + ((2*ks + lh) ^ swzK)) * 8];

        f16v S;
        {
            float ini = nearT ? 0.f : (farL ? qLn : qRn);
            #pragma unroll
            for (int r = 0; r < 16; r++) S[r] = ini;
        }
        #pragma unroll
        for (int ks = 0; ks < 4; ks++)
            S = MFMA32(ak32[ks], qa32[ks], S);

        // exp2 (+ Shaw near-diag bias), edge sums, in-place e-values
        if (nearT) {
            #pragma unroll
            for (int r = 0; r < 16; r++) {
                int Sl  = (r & 3) + 8*(r >> 2) + 4*lh;         // s-local row
                int rel = s0 + sh*32 + Sl - (t0 + t_bl);
                int rc  = rel < -16 ? -16 : (rel > 16 ? 16 : rel);
                float e = fexp2(S[r] + bu2f(qrk_s[t_bl*36 + rc + 16]));
                S[r] = e;
                if (rel <= -16)      L_p += e;
                else if (rel >= 16)  R_p += e;
                else                 diag16[t_bl*33 + rel + 15] = f2bu_fast(e);
            }
        } else {
            #pragma unroll
            for (int r = 0; r < 16; r++) S[r] = fexp2(S[r]);
        }

        // P -> in-register B fragments (k = s-local): pack pairs then swap
        unsigned int wl[8];
        #pragma unroll
        for (int g2 = 0; g2 < 4; g2++) {
            wl[2*g2]   = pk2_fast(S[4*g2],   S[4*g2+1]);
            wl[2*g2+1] = pk2_fast(S[4*g2+2], S[4*g2+3]);
        }
        plswap(wl[0], wl[2]);  plswap(wl[1], wl[3]);
        plswap(wl[4], wl[6]);  plswap(wl[5], wl[7]);
        union { unsigned int d[4]; s8b v; } pb0, pb1;
        pb0.d[0] = wl[0]; pb0.d[1] = wl[1]; pb0.d[2] = wl[2]; pb0.d[3] = wl[3];
        pb1.d[0] = wl[4]; pb1.d[1] = wl[5]; pb1.d[2] = wl[6]; pb1.d[3] = wl[7];

        // class rowsums via ones-MFMA: D[*][t] = sum_s P[s][t] (all rows eq.)
        if (nearT) {
            lsNa = MFMA32(ones, pb0.v, lsNa);
            lsNa = MFMA32(ones, pb1.v, lsNa);
        } else if (farL) {
            lsLa = MFMA32(ones, pb0.v, lsLa);
            lsLa = MFMA32(ones, pb1.v, lsLa);
        } else {
            lsRa = MFMA32(ones, pb0.v, lsRa);
            lsRa = MFMA32(ones, pb1.v, lsRa);
        }

        // O^T += V^T . P^T : A[m=d][k=s], 2 d-tiles x 2 k-slices
        #pragma unroll
        for (int dt = 0; dt < 2; dt++) {
            const int rV   = dt*32 + tloc;
            const int swzV = (rV & 7) ^ ((rV >> 3) & 1);
            s8b av0 = *(const s8b*)&v_s[cur][(rV*8 + ((sh*4 + 0 + lh) ^ swzV)) * 8];
            s8b av1 = *(const s8b*)&v_s[cur][(rV*8 + ((sh*4 + 2 + lh) ^ swzV)) * 8];
            O[dt] = MFMA32(av0, pb0.v, O[dt]);
            O[dt] = MFMA32(av1, pb1.v, O[dt]);
        }

        if (it + 1 < 32) {
            *(s8b*)&k_s[cur ^ 1][(w*64 + lane) * 8] = kr0;
            *(s8b*)&v_s[cur ^ 1][(w*64 + lane) * 8] = vr0;
        }
        __syncthreads();
    }

    // ---- epilogue ----
    // edge sums need the lane-pair combine; MFMA sums are already per-t.
    L_p += __shfl_xor(L_p, 32);  R_p += __shfl_xor(R_p, 32);
    if (lh == 0) {
        st3[sh][0][t_bl] = lsNa[0] + lsLa[0] + lsRa[0];
        st3[sh][1][t_bl] = lsLa[0] + L_p;
        st3[sh][2][t_bl] = lsRa[0] + R_p;
    }
    __syncthreads();

    // O reduction across s-half pairs through dead K/V buffers (f32, swizzled)
    float* obuf = (tg == 0) ? (float*)&k_s[0][0] :
                  (tg == 1) ? (float*)&k_s[1][0] :
                  (tg == 2) ? (float*)&v_s[0][0] : (float*)&v_s[1][0];
    const int xort = (tloc & 7) << 2;
    if (sh == 1) {
        #pragma unroll
        for (int dt = 0; dt < 2; dt++)
            #pragma unroll
            for (int r = 0; r < 16; r++) {
                int Sl = (r & 3) + 8*(r >> 2) + 4*lh;
                obuf[tloc*64 + ((dt*32 + Sl) ^ xort)] = O[dt][r];
            }
    }
    __syncthreads();
    if (sh == 0) {
        #pragma unroll
        for (int dt = 0; dt < 2; dt++)
            #pragma unroll
            for (int r = 0; r < 16; r++) {
                int Sl = (r & 3) + 8*(r >> 2) + 4*lh;
                O[dt][r] += obuf[tloc*64 + ((dt*32 + Sl) ^ xort)];
            }
    }
    __syncthreads();

    // stage rv TRANSPOSED into k_s[0] with the main-loop swizzle (r>=33 zero)
    {
        unsigned int* rvs = (unsigned int*)&k_s[0][0];
        for (int i = tid; i < 64 * 32; i += 512) {
            int d = i >> 5, dwL = i & 31;
            int r0 = dwL * 2, r1 = r0 + 1;
            float x0 = (r0 < 33) ? ld1d(rv_t, (size_t)r0 * 64 + d, f32m) : 0.f;
            float x1 = (r1 < 33) ? ld1d(rv_t, (size_t)r1 * 64 + d, f32m) : 0.f;
            int phys = d * 32 + (((dwL >> 2) ^ (d & 7) ^ ((d >> 3) & 1)) * 4) + (dwL & 3);
            rvs[phys] = pk2(x0, x1);
        }
    }
    // build P_extra[32][64] bf16 per t-group (cols 33..63 = 0)
    for (int j = 0; j < 16; j++) {
        int rloc = (w & 1) * 16 + j;
        int trow = (w >> 1) * 32 + rloc;
        int c = lane;
        unsigned short pv;
        if (c == 0)        pv = f2bu(st3[0][1][trow] + st3[1][1][trow]);
        else if (c == 32)  pv = f2bu(st3[0][2][trow] + st3[1][2][trow]);
        else if (c < 32)   pv = diag16[trow*33 + c - 1];
        else               pv = 0;
        p_s[w >> 1][rloc*72 + c] = pv;
    }
    __syncthreads();

    // ost aliases v_s (16 KB = 128 t-rows x 32 u32): safe — last v_s use
    // (obuf for tg 2,3) completed before the barrier above.
    unsigned int* ost = (unsigned int*)&v_s[0][0];
    if (sh == 0) {
        // O^T += rv^T . P_extra^T (32x32): B from p_s[tg], A from k_s[0]
        s8b pe[4];
        #pragma unroll
        for (int ks = 0; ks < 4; ks++)
            pe[ks] = *(const s8b*)&p_s[tg][tloc*72 + ks*16 + lh*8];
        #pragma unroll
        for (int dt = 0; dt < 2; dt++) {
            const int rD   = dt*32 + tloc;
            const int swzD = (rD & 7) ^ ((rD >> 3) & 1);
            #pragma unroll
            for (int ks = 0; ks < 4; ks++) {
                s8b ar = *(const s8b*)&k_s[0][(rD*8 + ((2*ks + lh) ^ swzD)) * 8];
                O[dt] = MFMA32(ar, pe[ks], O[dt]);
            }
        }
        // normalize + stage into ost (swizzled u32 pairs)
        const float linv = 1.f / (st3[0][0][t_bl] + st3[1][0][t_bl]);
        const int xr = (tloc & 7) << 2;
        #pragma unroll
        for (int dt = 0; dt < 2; dt++)
            #pragma unroll
            for (int g2 = 0; g2 < 4; g2++) {
                float v0 = O[dt][4*g2]   * linv;
                float v1 = O[dt][4*g2+1] * linv;
                float v2 = O[dt][4*g2+2] * linv;
                float v3 = O[dt][4*g2+3] * linv;
                int col = dt*16 + g2*4 + lh*2;   // u32 col (0..30, even)
                *(uint2*)&ost[t_bl*32 + (col ^ xr)] =
                    make_uint2(pk2(v0, v1), pk2(v2, v3));
            }
    }
    __syncthreads();
    // coalesced stores: 8 threads x 16B = one 128B run per t-row
    {
        const int bb = n >> 4, hh = n & 15;
        #pragma unroll
        for (int i2 = 0; i2 < 2; i2++) {
            int li = i2*512 + tid;                // 0..1023
            int row = li >> 3, ch = li & 7;
            int xr = (row & 7) << 2;
            uint4 vd = *(const uint4*)&ost[row*32 + ((ch*4) ^ xr)];
            size_t du = ((((size_t)(t0 + row) * B_ + bb) * E_) >> 1) + hh*32 + ch*4;
            *(uint4*)((unsigned int*)aout + du) = vd;
        }
    }
}

// ---------------------------------------------------------------------------
// Output projection, bf16 MFMA GEMM. R22: 64x128 tiles, grid 512 = 2
// blocks/CU. f32 output path (active for f32 inputs) keeps direct stores.
// ---------------------------------------------------------------------------
__global__ __launch_bounds__(256, 2) void out_gemm(
    const unsigned short* __restrict__ A,
    const unsigned short* __restrict__ Wob, const unsigned short* __restrict__ bob,
    void* __restrict__ out, const int* __restrict__ flag)
{
    const bool f32m = (*flag != 0);
    const int bid = blockIdx.x;            // 512 blocks
    const int r_ = bid & 7, s_ = bid >> 3; // s_ in [0,64)
    const int g = r_ + 8 * (s_ >> 3);      // [0,64) m-tile
    const int m0 = g * 64;
    const int e0 = (s_ & 7) * 128;

    const int tid = threadIdx.x, w = tid >> 6, lane = tid & 63;
    const int quad = lane >> 4, lc = lane & 15;
    const int wx = w & 1, wy = w >> 1;

    __shared__ unsigned short smem[12288];
    #define A_S(c) (&smem[(c) * 2048])
    #define B_S(c) (&smem[4096 + (c) * 4096])

    f4 acc[2][4];
    #pragma unroll
    for (int i = 0; i < 2; i++)
        #pragma unroll
        for (int j = 0; j < 4; j++) acc[i][j] = (f4){0.f, 0.f, 0.f, 0.f};

    const int gr = lane >> 2;
    const int gc = (lane & 3) ^ (gr & 3);
    const size_t aoff = (size_t)(m0 + w*16 + gr) * E_ + gc*8;   // 16 rows/wave
    const size_t boff = (size_t)(e0 + w*32 + gr) * E_ + gc*8;

    glds16(A + aoff, &A_S(0)[(w*64) * 8]);
    #pragma unroll
    for (int j = 0; j < 2; j++)
        glds16(Wob + boff + (size_t)j*16*E_, &B_S(0)[(w*128 + j*64) * 8]);
    __syncthreads();

    const int fcA = quad ^ (lc & 3);
    for (int k0 = 0; k0 < E_; k0 += 32) {
        const int cur = (k0 >> 5) & 1;
        if (k0 + 32 < E_) {
            glds16(A + aoff + k0 + 32, &A_S(cur^1)[(w*64) * 8]);
            #pragma unroll
            for (int j = 0; j < 2; j++)
                glds16(Wob + boff + (size_t)j*16*E_ + k0 + 32, &B_S(cur^1)[(w*128 + j*64) * 8]);
        }
        s8b af[2], bfr[4];
        #pragma unroll
        for (int i = 0; i < 2; i++)
            af[i]  = *(const s8b*)&A_S(cur)[((wy*32 + i*16 + lc)*4 + fcA) * 8];
        #pragma unroll
        for (int i = 0; i < 4; i++)
            bfr[i] = *(const s8b*)&B_S(cur)[((wx*64 + i*16 + lc)*4 + fcA) * 8];
        #pragma unroll
        for (int ms = 0; ms < 2; ms++)
            #pragma unroll
            for (int ns = 0; ns < 4; ns++)
                acc[ms][ns] = MFMA_B16(af[ms], bfr[ns], acc[ms][ns]);
        __syncthreads();
    }

    float bias_v[4];
    #pragma unroll
    for (int ns = 0; ns < 4; ns++) bias_v[ns] = bu2f(bob[e0 + wx*64 + ns*16 + lc]);

    if (f32m) {
        #pragma unroll
        for (int ms = 0; ms < 2; ms++)
            #pragma unroll
            for (int ns = 0; ns < 4; ns++)
                #pragma unroll
                for (int r2 = 0; r2 < 4; r2++) {
                    float val = acc[ms][ns][r2] + bias_v[ns];
                    size_t m = m0 + wy*32 + ms*16 + quad*4 + r2;
                    int e = e0 + wx*64 + ns*16 + lc;
                    ((float*)out)[m * E_ + e] = val;
                }
    } else {
        unsigned int* cst = (unsigned int*)&smem[0];
        __syncthreads();
        #pragma unroll
        for (int ms = 0; ms < 2; ms++)
            #pragma unroll
            for (int ns = 0; ns < 4; ns++)
                #pragma unroll
                for (int r2 = 0; r2 < 4; r2++) {
                    float val = acc[ms][ns][r2] + bias_v[ns];
                    float nb = __shfl_xor(val, 1);
                    if (!(lane & 1)) {
                        int mi = wy*32 + ms*16 + quad*4 + r2;   // 0..63
                        int ei = wx*64 + ns*16 + lc;            // even
                        int col = ei >> 1;                      // 0..63
                        cst[mi*64 + (col ^ ((mi & 7) << 2))] = pk2(val, nb);
                    }
                }
        __syncthreads();
        unsigned int* dst32 = (unsigned int*)out;
        #pragma unroll
        for (int i = 0; i < 4; i++) {
            const int li  = i*256 + tid;              // 0..1023
            const int row = li >> 4;                  // 0..63
            const int ch  = li & 15;                  // 16 chunks x 16B
            uint4 vd = *(const uint4*)&cst[row*64 + ((ch*4) ^ ((row & 7) << 2))];
            const size_t du = ((size_t)(m0 + row) * E_ + e0) / 2 + ch*4;
            *(uint4*)&dst32[du] = vd;
        }
    }
    #undef A_S
    #undef B_S
}

extern "C" void kernel_launch(void* const* d_in, const int* in_sizes, int n_in,
                              void* d_out, int out_size, void* d_ws, size_t ws_size,
                              hipStream_t stream) {
    const void* x  = d_in[0];
    const void* Wq = d_in[1];  const void* bq = d_in[2];
    const void* Wk = d_in[3];  const void* bk = d_in[4];
    const void* Wv = d_in[5];  const void* bv = d_in[6];
    const void* Wo = d_in[7];  const void* bo = d_in[8];
    const void* rk = d_in[9];  const void* rv = d_in[10];

    int* flag = (int*)d_ws;
    const size_t HTD = (size_t)NH_ * T_ * D_;        // 4,194,304 elems
    unsigned short* qw = (unsigned short*)((char*)d_ws + 256);
    unsigned short* kw = qw + HTD;
    unsigned short* vw = kw + HTD;                   // V^T [N][D][T] bf16
    unsigned short* aw = vw + HTD;                   // [4096][1024] bf16 pre-Wo
    unsigned short* xw = aw + (size_t)M_ * E_;       // x as bf16 (8 MB)
    unsigned short* Ww = xw + (size_t)M_ * E_;       // Wq,Wk,Wv,Wo bf16 (8 MB)
    unsigned short* bw = Ww + (size_t)4 * E_ * E_;   // bq,bk,bv,bo bf16 (8 KB)
    // ws use: ~48 MB

    cvt_bf16<<<dim3(4100), 256, 0, stream>>>(
        x, Wq, Wk, Wv, Wo, bq, bk, bv, bo, xw, Ww, bw, flag);
    qkv_gemm<<<dim3(768), 256, 0, stream>>>(xw, Ww, bw, qw, kw, vw);
    attn_mfma<<<dim3(NH_ * (T_/128)), 512, 0, stream>>>(qw, kw, vw, rk, rv, aw, flag);
    out_gemm<<<dim3(512), 256, 0, stream>>>(aw, Ww + (size_t)3*E_*E_, bw + 3*E_,
                                            d_out, flag);
}

// Round 15
// 210.088 us; speedup vs baseline: 2.5293x; 2.5293x over previous
//
#include <hip/hip_runtime.h>
#include <hip/hip_bf16.h>
#include <math.h>

#define T_   2048
#define B_   2
#define E_   1024
#define H_   16
#define D_   64
#define NH_  32
#define M_   4096

typedef __attribute__((ext_vector_type(8))) short s8b;   // 8 bf16 (4 VGPRs)
typedef __attribute__((ext_vector_type(4))) float f4;    // 4 f32 acc
typedef __attribute__((ext_vector_type(16))) float f16v; // 32x32 MFMA acc

#define MFMA_B16(a,b,c) __builtin_amdgcn_mfma_f32_16x16x32_bf16(a,b,c,0,0,0)
#define MFMA32(a,b,c)   __builtin_amdgcn_mfma_f32_32x32x16_bf16(a,b,c,0,0,0)
#define LOG2E 1.44269504088896f

__device__ __forceinline__ unsigned short f2bu(float f) {
    union { __hip_bfloat16 h; unsigned short u; } cv;
    cv.h = __float2bfloat16(f);
    return cv.u;
}
// fast bf16: round-half-up truncation (positive finite values) — 2 VALU ops
__device__ __forceinline__ unsigned short f2bu_fast(float f) {
    return (unsigned short)((__float_as_uint(f) + 0x8000u) >> 16);
}
__device__ __forceinline__ float bu2f(unsigned short u) {
    union { __hip_bfloat16 h; unsigned short u; } cv; cv.u = u;
    return __bfloat162float(cv.h);
}
__device__ __forceinline__ unsigned int pk2(float a, float b) {
    return (unsigned int)f2bu(a) | ((unsigned int)f2bu(b) << 16);
}
// pack two f32 -> packed bf16 pair with round-half-up (cheap)
__device__ __forceinline__ unsigned int pk2_fast(float a, float b) {
    return ((__float_as_uint(a) + 0x8000u) >> 16) |
           ((__float_as_uint(b) + 0x8000u) & 0xFFFF0000u);
}
// raw v_exp_f32 — exp2f() without fast-math expands to a denorm-guard
// sequence (~12 extra VALU ops); attention scores never reach denormals.
__device__ __forceinline__ float fexp2(float x) {
    return __builtin_amdgcn_exp2f(x);
}
__device__ __forceinline__ float ld1d(const void* p, size_t idx, bool f32) {
    return f32 ? ((const float*)p)[idx] : bu2f(((const unsigned short*)p)[idx]);
}
// swap: a' = {a.lo32, b.lo32}, b' = {a.hi32, b.hi32} (v_permlane32_swap_b32)
__device__ __forceinline__ void plswap(unsigned int &a, unsigned int &b) {
    auto r = __builtin_amdgcn_permlane32_swap(a, b, false, false);
    a = r[0]; b = r[1];
}
// async global->LDS, 16 B per lane (GEMMs only — attn uses register prefetch
// because its per-tile barrier drains vmcnt(0) and exposes the DMA latency)
__device__ __forceinline__ void glds16(const unsigned short* g, unsigned short* l) {
    __builtin_amdgcn_global_load_lds(
        (const __attribute__((address_space(1))) unsigned int*)g,
        (__attribute__((address_space(3))) unsigned int*)l, 16, 0, 0);
}
// dtype detect, wave-local (identical result in every wave): sample 64 u16
// words of x; bf16 data -> ~all exponent fields sane; f32-as-u16 -> ~half.
__device__ __forceinline__ bool detect_f32(const unsigned short* q16) {
    int e = (q16[threadIdx.x & 63] >> 7) & 0xFF;
    bool sane = (e == 0) || (e >= 97 && e <= 157);
    unsigned long long m = __ballot(sane);
    return __popcll(m) < 56;   // true = f32 inputs
}

// ---------------------------------------------------------------------------
// One-pass f32->bf16 conversion of x, Wq..Wo, bq..bo into ws. R21: exact 1D
// grid (4100 blocks). Also publishes the dtype flag.
// ---------------------------------------------------------------------------
__global__ __launch_bounds__(256) void cvt_bf16(
    const void* __restrict__ x,
    const void* __restrict__ Wq, const void* __restrict__ Wk,
    const void* __restrict__ Wv, const void* __restrict__ Wo,
    const void* __restrict__ bq, const void* __restrict__ bk,
    const void* __restrict__ bv, const void* __restrict__ bo,
    unsigned short* __restrict__ xw, unsigned short* __restrict__ Ww,
    unsigned short* __restrict__ bw, int* __restrict__ flag)
{
    const bool f32m = detect_f32((const unsigned short*)x);
    const int bid = blockIdx.x;
    if (bid == 0 && threadIdx.x == 0)
        *flag = f32m ? 1 : 0;
    int y, lb;
    if (bid < 2048)       { y = 0;                      lb = bid; }
    else if (bid < 4096)  { y = 1 + ((bid - 2048) >> 9); lb = (bid - 2048) & 511; }
    else                  { y = 5 + (bid - 4096);        lb = 0; }
    const void* src; unsigned short* dst; int n;
    if (y == 0)      { src = x; dst = xw; n = M_ * E_; }
    else if (y <= 4) {
        src = (y == 1) ? Wq : (y == 2) ? Wk : (y == 3) ? Wv : Wo;
        dst = Ww + (size_t)(y - 1) * E_ * E_; n = E_ * E_;
    } else {
        src = (y == 5) ? bq : (y == 6) ? bk : (y == 7) ? bv : bo;
        dst = bw + (size_t)(y - 5) * E_; n = E_;
    }
    int i = (lb * 256 + threadIdx.x) * 8;
    if (i >= n) return;
    if (f32m) {
        const float* s = (const float*)src + i;
        float4 f0 = *(const float4*)s, f1 = *(const float4*)(s + 4);
        union { unsigned int d[4]; s8b v; } u;
        u.d[0] = pk2(f0.x, f0.y); u.d[1] = pk2(f0.z, f0.w);
        u.d[2] = pk2(f1.x, f1.y); u.d[3] = pk2(f1.z, f1.w);
        *(s8b*)(dst + i) = u.v;
    } else {
        *(s8b*)(dst + i) = *(const s8b*)((const unsigned short*)src + i);
    }
}

// ---------------------------------------------------------------------------
// QKV projection, bf16 MFMA GEMM, XCD swizzle, glds staging (xor-swizzled),
// double-buffered single-barrier. p==2 (V) written TRANSPOSED [N][D][T] via
// LDS-staged coalesced stores (R20). R21: Q/K epilogue ALSO LDS-staged.
// ---------------------------------------------------------------------------
__global__ __launch_bounds__(256, 3) void qkv_gemm(
    const unsigned short* __restrict__ xw, const unsigned short* __restrict__ Ww,
    const unsigned short* __restrict__ bw,
    unsigned short* __restrict__ qo, unsigned short* __restrict__ ko,
    unsigned short* __restrict__ vo)
{
    const int bid = blockIdx.x;            // 768 blocks
    const int r_ = bid & 7, s_ = bid >> 3;
    const int g = r_ + 8 * (s_ >> 3);      // group in [0,96): (m,p)
    const int e0 = (s_ & 7) * 128;
    const int m0 = (g & 31) * 128;
    const int p  = g >> 5;
    const unsigned short* W    = Ww + (size_t)p * E_ * E_;
    const unsigned short* bias = bw + (size_t)p * E_;
    const float scale = (p == 0) ? 0.125f * LOG2E : 1.0f;

    const int tid = threadIdx.x, w = tid >> 6, lane = tid & 63;
    const int quad = lane >> 4, lc = lane & 15;
    const int wx = w & 1, wy = w >> 1;

    __shared__ unsigned short smem[4][128 * 32];

    f4 acc[4][4];
    #pragma unroll
    for (int i = 0; i < 4; i++)
        #pragma unroll
        for (int j = 0; j < 4; j++) acc[i][j] = (f4){0.f, 0.f, 0.f, 0.f};

    const int gr = lane >> 2;
    const int gc = (lane & 3) ^ ((lane >> 2) & 3);
    const size_t aoff = (size_t)(m0 + w*32 + gr) * E_ + gc*8;
    const size_t boff = (size_t)(e0 + w*32 + gr) * E_ + gc*8;

    #pragma unroll
    for (int j = 0; j < 2; j++) {
        glds16(xw + aoff + (size_t)j*16*E_, &smem[0][(w*128 + j*64) * 8]);
        glds16(W  + boff + (size_t)j*16*E_, &smem[2][(w*128 + j*64) * 8]);
    }
    __syncthreads();

    const int fcA = quad ^ (lc & 3);
    for (int k0 = 0; k0 < E_; k0 += 32) {
        const int cur = (k0 >> 5) & 1;
        if (k0 + 32 < E_) {
            #pragma unroll
            for (int j = 0; j < 2; j++) {
                glds16(xw + aoff + (size_t)j*16*E_ + k0 + 32, &smem[cur^1][(w*128 + j*64) * 8]);
                glds16(W  + boff + (size_t)j*16*E_ + k0 + 32, &smem[2 + (cur^1)][(w*128 + j*64) * 8]);
            }
        }
        s8b af[4], bfr[4];
        #pragma unroll
        for (int i = 0; i < 4; i++)
            af[i]  = *(const s8b*)&smem[cur][((wy*64 + i*16 + lc)*4 + fcA) * 8];
        #pragma unroll
        for (int i = 0; i < 4; i++)
            bfr[i] = *(const s8b*)&smem[2 + cur][((wx*64 + i*16 + lc)*4 + fcA) * 8];
        #pragma unroll
        for (int ms = 0; ms < 4; ms++)
            #pragma unroll
            for (int ns = 0; ns < 4; ns++)
                acc[ms][ns] = MFMA_B16(af[ms], bfr[ns], acc[ms][ns]);
        __syncthreads();
    }

    float bias_v[4];
    #pragma unroll
    for (int ns = 0; ns < 4; ns++) bias_v[ns] = bu2f(bias[e0 + wx*64 + ns*16 + lc]);

    unsigned int* cst = (unsigned int*)&smem[0][0];   // 8192 u32 = 32 KB
    if (p < 2) {
        // ---- Q/K epilogue, LDS-staged ----
        #pragma unroll
        for (int ms = 0; ms < 4; ms++)
            #pragma unroll
            for (int ns = 0; ns < 4; ns++)
                #pragma unroll
                for (int r2 = 0; r2 < 4; r2++) {
                    float val = (acc[ms][ns][r2] + bias_v[ns]) * scale;
                    float nb = __shfl_xor(val, 1);
                    if (!(lane & 1)) {
                        int mi = wy*64 + ms*16 + quad*4 + r2;     // 0..127
                        int ei = wx*64 + ns*16 + lc;              // 0..127, even
                        int row = ((mi & 1) * 2 + (ei >> 6)) * 64 + (mi >> 1);
                        int col = (ei & 63) >> 1;                 // 0..31
                        cst[row*32 + (col ^ ((row & 7) << 2))] = pk2(val, nb);
                    }
                }
        __syncthreads();
        unsigned int* dst32 = (unsigned int*)((p == 0) ? qo : ko);
        #pragma unroll
        for (int i = 0; i < 8; i++) {
            const int li  = i*256 + tid;              // 0..2047
            const int row = li >> 3;                  // 0..255
            const int ch  = li & 7;                   // 16B chunk
            uint4 vd = *(const uint4*)&cst[row*32 + ((ch*4) ^ ((row & 7) << 2))];
            const int bb = row >> 7, hh = (row >> 6) & 1, tq = row & 63;
            const size_t du = (((size_t)(bb*H_ + (e0 >> 6) + hh) * T_
                                + (m0 >> 1) + tq) << 5) + ch*4;
            *(uint4*)&dst32[du] = vd;
        }
    } else {
        // ---- V epilogue, LDS-staged (R20) ----
        #pragma unroll
        for (int ms = 0; ms < 4; ms++) {
            const int tq = wy*16 + ms*4 + quad;           // [0,32)
            #pragma unroll
            for (int ns = 0; ns < 4; ns++) {
                const int e_l = wx*64 + ns*16 + lc;       // [0,128)
                const int x = (e_l & 7) << 2;
                float v0 = acc[ms][ns][0] + bias_v[ns];
                float v1 = acc[ms][ns][1] + bias_v[ns];
                float v2 = acc[ms][ns][2] + bias_v[ns];
                float v3 = acc[ms][ns][3] + bias_v[ns];
                cst[e_l*64 + ( tq       ^ x)] = pk2(v0, v2);   // bb = 0
                cst[e_l*64 + ((32 + tq) ^ x)] = pk2(v1, v3);   // bb = 1
            }
        }
        __syncthreads();
        #pragma unroll
        for (int i = 0; i < 8; i++) {
            const int li  = i*256 + tid;                  // [0,2048)
            const int e_l = li >> 4;
            const int bb  = (li >> 3) & 1;
            const int ch  = li & 7;                       // 16B chunk
            const int x   = (e_l & 7) << 2;
            uint4 vd = *(const uint4*)&cst[e_l*64 + ((bb*32 + ch*4) ^ x)];
            const int e = e0 + e_l, h = e >> 6, d = e & 63;
            const size_t du = ((size_t)(bb*H_ + h) * 64 + d) * (T_/2)
                              + (m0 >> 2) + ch*4;
            *(uint4*)((unsigned int*)vo + du) = vd;
        }
    }
}

// ---------------------------------------------------------------------------
// Flash attention with Shaw bias — R25: R23 core (32x32 MFMA, in-register P
// via permlane32_swap, scalar VALU rowsums — VGPR 64, no spill) + R24's
// register-free aout LDS-staged store. R24's ones-MFMA rowsums (3 x f16v =
// +48 VGPR) blew the 128-VGPR budget at 4 waves/SIMD -> scratch spill ->
// 1.5 GB HBM traffic, 5.6x regression. REVERTED; never exceed ~100 VGPR
// in this kernel.
// ---------------------------------------------------------------------------
__global__ __launch_bounds__(512, 4) void attn_mfma(
    const unsigned short* __restrict__ q, const unsigned short* __restrict__ k,
    const unsigned short* __restrict__ v,
    const void* __restrict__ rk_t, const void* __restrict__ rv_t,
    unsigned short* __restrict__ aout, const int* __restrict__ flag)
{
    const bool f32m = (*flag != 0);
    const int bid = blockIdx.x;
    const int n = bid & 31, qt = bid >> 5;
    const int t0 = qt * 128;
    const int tid = threadIdx.x, w = tid >> 6, lane = tid & 63;
    const int quad = lane >> 4, lc = lane & 15;
    const int tg = w >> 1, sh = w & 1;          // t-group, s-half
    const int lh = lane >> 5, tloc = lane & 31; // half-wave, local t (or row)
    const int t_bl = tg * 32 + tloc;            // block-local t of this lane

    __shared__ unsigned short k_s[2][64 * 64];   // K[s][d] swizzled; epi: O-buf/rv^T
    __shared__ unsigned short v_s[2][64 * 64];   // V^T[d][s] swizzled; epi: O-buf/out
    __shared__ unsigned short p_s[4][32 * 72];   // rk staging / P_extra per t-group
    __shared__ unsigned short qrk_s[128 * 36];   // qrk[t_local][r] bf16 (log2 dom.)
    __shared__ unsigned short diag16[128 * 33];  // e-values at |rel|<16, bf16
    __shared__ float st3[2][3][128];             // per-s-half {l, L, R} per t

    const unsigned short* qn = q + ((size_t)n * T_ + t0) * D_;
    const unsigned short* kn = k + (size_t)n * T_ * D_;
    const unsigned short* vn = v + (size_t)n * D_ * T_;   // V^T [D][T]

    for (int i = tid; i < 128 * 33; i += 512) diag16[i] = 0;

    // stage rk (bf16, padded [48][72], rows>=33 zero) into p_s area
    unsigned int* rks = (unsigned int*)&p_s[0][0];
    for (int i = tid; i < 48 * 36; i += 512) {
        int r = i / 36, c2 = i % 36;
        unsigned int val = 0;
        if (r < 33 && c2 < 32)
            val = pk2(ld1d(rk_t, r*64 + 2*c2, f32m), ld1d(rk_t, r*64 + 2*c2 + 1, f32m));
        rks[i] = val;
    }
    __syncthreads();

    // qrk[t][r] = q[t] . rk[r] via 16x16 MFMA (prologue-only, rows w*16..+15)
    {
        s8b qa16[2];
        #pragma unroll
        for (int kf = 0; kf < 2; kf++)
            qa16[kf] = *(const s8b*)(qn + (size_t)(w*16 + lc) * D_ + kf*32 + quad*8);
        for (int nt = 0; nt < 3; nt++) {
            s8b b0 = *(const s8b*)((const unsigned short*)rks + (nt*16 + lc)*72 + quad*8);
            s8b b1 = *(const s8b*)((const unsigned short*)rks + (nt*16 + lc)*72 + 32 + quad*8);
            f4 a = (f4){0.f, 0.f, 0.f, 0.f};
            a = MFMA_B16(qa16[0], b0, a);
            a = MFMA_B16(qa16[1], b1, a);
            #pragma unroll
            for (int r = 0; r < 4; r++) {
                float nb = __shfl_xor(a[r], 1);
                int col = nt*16 + lc;
                if (!(lane & 1) && col < 34)
                    ((unsigned int*)qrk_s)[(w*16 + quad*4 + r)*18 + (col >> 1)] = pk2(a[r], nb);
            }
        }
    }
    __syncthreads();   // rk staging (aliased with p_s) free after this

    // Q fragments, 32x32 B-operand: B[n=t=lane&31][k=d=16*ks+8*lh+j]
    s8b qa32[4];
    #pragma unroll
    for (int ks = 0; ks < 4; ks++)
        qa32[ks] = *(const s8b*)(qn + (size_t)t_bl * D_ + ks*16 + lh*8);

    const float qLn = bu2f(qrk_s[t_bl*36 + 0]);
    const float qRn = bu2f(qrk_s[t_bl*36 + 32]);
    float L_p = 0.f, R_p = 0.f, sN = 0.f, sL = 0.f, sR = 0.f;
    f16v O[2];
    #pragma unroll
    for (int dt = 0; dt < 2; dt++)
        #pragma unroll
        for (int r = 0; r < 16; r++) O[dt][r] = 0.f;

    // staging: row = w*8 + (lane>>3); phys chunk = lane&7; source chunk
    // gcc = phys ^ (row&7) ^ ((row>>3)&1)  [row&7 = lane>>3, row>>3 = w]
    const int grr = lane >> 3;
    const int gcc = (lane & 7) ^ grr ^ (w & 1);
    const size_t koff = (size_t)(w*8 + grr) * D_ + gcc*8;   // + s0*D_
    const size_t voff = (size_t)(w*8 + grr) * T_ + gcc*8;   // + s0

    // tile-order stagger: co-resident pair (bid, bid+256) -> opposite phase
    const int kts = ((bid >> 8) & 1) * 16;

    s8b kr0 = *(const s8b*)(kn + koff + (size_t)(kts * 64) * D_);
    s8b vr0 = *(const s8b*)(vn + voff + kts * 64);
    *(s8b*)&k_s[0][(w*64 + lane) * 8] = kr0;
    *(s8b*)&v_s[0][(w*64 + lane) * 8] = vr0;
    __syncthreads();

    const int rK   = sh*32 + tloc;                       // K row in k_s
    const int swzK = (rK & 7) ^ ((rK >> 3) & 1);
    for (int it = 0; it < 32; it++) {
        const int kt = (it + kts) & 31;
        const int s0 = kt * 64;
        const int cur = it & 1;
        if (it + 1 < 32) {
            const int s0n = ((it + 1 + kts) & 31) * 64;
            kr0 = *(const s8b*)(kn + koff + (size_t)s0n * D_);
            vr0 = *(const s8b*)(vn + voff + s0n);
        }

        const bool farL  = (s0 + 63 < t0 - 16);
        const bool farR  = (s0 > t0 + 143);
        const bool nearT = !farL && !farR;

        // K fragments, A-operand: A[m=s=rK][k=d=16*ks+8*lh+j]
        s8b ak32[4];
        #pragma unroll
        for (int ks = 0; ks < 4; ks++)
            ak32[ks] = *(const s8b*)&k_s[cur][(rK*8 + ((2*ks + lh) ^ swzK)) * 8];

        f16v S;
        {
            float ini = nearT ? 0.f : (farL ? qLn : qRn);
            #pragma unroll
            for (int r = 0; r < 16; r++) S[r] = ini;
        }
        #pragma unroll
        for (int ks = 0; ks < 4; ks++)
            S = MFMA32(ak32[ks], qa32[ks], S);

        // exp2 (+ Shaw near-diag bias), class sums, in-place e-values
        if (nearT) {
            #pragma unroll
            for (int r = 0; r < 16; r++) {
                int Sl  = (r & 3) + 8*(r >> 2) + 4*lh;         // s-local row
                int rel = s0 + sh*32 + Sl - (t0 + t_bl);
                int rc  = rel < -16 ? -16 : (rel > 16 ? 16 : rel);
                float e = fexp2(S[r] + bu2f(qrk_s[t_bl*36 + rc + 16]));
                S[r] = e;
                if (rel <= -16)      L_p += e;
                else if (rel >= 16)  R_p += e;
                else                 diag16[t_bl*33 + rel + 15] = f2bu_fast(e);
            }
        } else {
            #pragma unroll
            for (int r = 0; r < 16; r++) S[r] = fexp2(S[r]);
        }
        {
            float ss = ((S[0]+S[1])+(S[2]+S[3])) + ((S[4]+S[5])+(S[6]+S[7]))
                     + ((S[8]+S[9])+(S[10]+S[11])) + ((S[12]+S[13])+(S[14]+S[15]));
            if (nearT) sN += ss; else if (farL) sL += ss; else sR += ss;
        }

        // P -> in-register B fragments (k = s-local): pack pairs then swap
        unsigned int wl[8];
        #pragma unroll
        for (int g2 = 0; g2 < 4; g2++) {
            wl[2*g2]   = pk2_fast(S[4*g2],   S[4*g2+1]);
            wl[2*g2+1] = pk2_fast(S[4*g2+2], S[4*g2+3]);
        }
        plswap(wl[0], wl[2]);  plswap(wl[1], wl[3]);
        plswap(wl[4], wl[6]);  plswap(wl[5], wl[7]);
        union { unsigned int d[4]; s8b v; } pb0, pb1;
        pb0.d[0] = wl[0]; pb0.d[1] = wl[1]; pb0.d[2] = wl[2]; pb0.d[3] = wl[3];
        pb1.d[0] = wl[4]; pb1.d[1] = wl[5]; pb1.d[2] = wl[6]; pb1.d[3] = wl[7];

        // O^T += V^T . P^T : A[m=d][k=s], 2 d-tiles x 2 k-slices
        #pragma unroll
        for (int dt = 0; dt < 2; dt++) {
            const int rV   = dt*32 + tloc;
            const int swzV = (rV & 7) ^ ((rV >> 3) & 1);
            s8b av0 = *(const s8b*)&v_s[cur][(rV*8 + ((sh*4 + 0 + lh) ^ swzV)) * 8];
            s8b av1 = *(const s8b*)&v_s[cur][(rV*8 + ((sh*4 + 2 + lh) ^ swzV)) * 8];
            O[dt] = MFMA32(av0, pb0.v, O[dt]);
            O[dt] = MFMA32(av1, pb1.v, O[dt]);
        }

        if (it + 1 < 32) {
            *(s8b*)&k_s[cur ^ 1][(w*64 + lane) * 8] = kr0;
            *(s8b*)&v_s[cur ^ 1][(w*64 + lane) * 8] = vr0;
        }
        __syncthreads();
    }

    // ---- epilogue ----
    // combine lane pairs (t in lanes t and t+32), publish per-s-half sums
    sN += __shfl_xor(sN, 32);  sL += __shfl_xor(sL, 32);  sR += __shfl_xor(sR, 32);
    L_p += __shfl_xor(L_p, 32);  R_p += __shfl_xor(R_p, 32);
    if (lh == 0) {
        st3[sh][0][t_bl] = sN + sL + sR;
        st3[sh][1][t_bl] = sL + L_p;
        st3[sh][2][t_bl] = sR + R_p;
    }
    __syncthreads();

    // O reduction across s-half pairs through dead K/V buffers (f32, swizzled)
    float* obuf = (tg == 0) ? (float*)&k_s[0][0] :
                  (tg == 1) ? (float*)&k_s[1][0] :
                  (tg == 2) ? (float*)&v_s[0][0] : (float*)&v_s[1][0];
    const int xort = (tloc & 7) << 2;
    if (sh == 1) {
        #pragma unroll
        for (int dt = 0; dt < 2; dt++)
            #pragma unroll
            for (int r = 0; r < 16; r++) {
                int Sl = (r & 3) + 8*(r >> 2) + 4*lh;
                obuf[tloc*64 + ((dt*32 + Sl) ^ xort)] = O[dt][r];
            }
    }
    __syncthreads();
    if (sh == 0) {
        #pragma unroll
        for (int dt = 0; dt < 2; dt++)
            #pragma unroll
            for (int r = 0; r < 16; r++) {
                int Sl = (r & 3) + 8*(r >> 2) + 4*lh;
                O[dt][r] += obuf[tloc*64 + ((dt*32 + Sl) ^ xort)];
            }
    }
    __syncthreads();

    // stage rv TRANSPOSED into k_s[0] with the main-loop swizzle (r>=33 zero)
    {
        unsigned int* rvs = (unsigned int*)&k_s[0][0];
        for (int i = tid; i < 64 * 32; i += 512) {
            int d = i >> 5, dwL = i & 31;
            int r0 = dwL * 2, r1 = r0 + 1;
            float x0 = (r0 < 33) ? ld1d(rv_t, (size_t)r0 * 64 + d, f32m) : 0.f;
            float x1 = (r1 < 33) ? ld1d(rv_t, (size_t)r1 * 64 + d, f32m) : 0.f;
            int phys = d * 32 + (((dwL >> 2) ^ (d & 7) ^ ((d >> 3) & 1)) * 4) + (dwL & 3);
            rvs[phys] = pk2(x0, x1);
        }
    }
    // build P_extra[32][64] bf16 per t-group (cols 33..63 = 0)
    for (int j = 0; j < 16; j++) {
        int rloc = (w & 1) * 16 + j;
        int trow = (w >> 1) * 32 + rloc;
        int c = lane;
        unsigned short pv;
        if (c == 0)        pv = f2bu(st3[0][1][trow] + st3[1][1][trow]);
        else if (c == 32)  pv = f2bu(st3[0][2][trow] + st3[1][2][trow]);
        else if (c < 32)   pv = diag16[trow*33 + c - 1];
        else               pv = 0;
        p_s[w >> 1][rloc*72 + c] = pv;
    }
    __syncthreads();

    // ost aliases v_s (16 KB = 128 t-rows x 32 u32): safe — last v_s use
    // (obuf for tg 2,3) completed before the barrier above.
    unsigned int* ost = (unsigned int*)&v_s[0][0];
    if (sh == 0) {
        // O^T += rv^T . P_extra^T (32x32): B from p_s[tg], A from k_s[0]
        s8b pe[4];
        #pragma unroll
        for (int ks = 0; ks < 4; ks++)
            pe[ks] = *(const s8b*)&p_s[tg][tloc*72 + ks*16 + lh*8];
        #pragma unroll
        for (int dt = 0; dt < 2; dt++) {
            const int rD   = dt*32 + tloc;
            const int swzD = (rD & 7) ^ ((rD >> 3) & 1);
            #pragma unroll
            for (int ks = 0; ks < 4; ks++) {
                s8b ar = *(const s8b*)&k_s[0][(rD*8 + ((2*ks + lh) ^ swzD)) * 8];
                O[dt] = MFMA32(ar, pe[ks], O[dt]);
            }
        }
        // normalize + stage into ost (swizzled u32 pairs)
        const float linv = 1.f / (st3[0][0][t_bl] + st3[1][0][t_bl]);
        const int xr = (tloc & 7) << 2;
        #pragma unroll
        for (int dt = 0; dt < 2; dt++)
            #pragma unroll
            for (int g2 = 0; g2 < 4; g2++) {
                float v0 = O[dt][4*g2]   * linv;
                float v1 = O[dt][4*g2+1] * linv;
                float v2 = O[dt][4*g2+2] * linv;
                float v3 = O[dt][4*g2+3] * linv;
                int col = dt*16 + g2*4 + lh*2;   // u32 col (0..30, even)
                *(uint2*)&ost[t_bl*32 + (col ^ xr)] =
                    make_uint2(pk2(v0, v1), pk2(v2, v3));
            }
    }
    __syncthreads();
    // coalesced stores: 8 threads x 16B = one 128B run per t-row
    {
        const int bb = n >> 4, hh = n & 15;
        #pragma unroll
        for (int i2 = 0; i2 < 2; i2++) {
            int li = i2*512 + tid;                // 0..1023
            int row = li >> 3, ch = li & 7;
            int xr = (row & 7) << 2;
            uint4 vd = *(const uint4*)&ost[row*32 + ((ch*4) ^ xr)];
            size_t du = ((((size_t)(t0 + row) * B_ + bb) * E_) >> 1) + hh*32 + ch*4;
            *(uint4*)((unsigned int*)aout + du) = vd;
        }
    }
}

// ---------------------------------------------------------------------------
// Output projection, bf16 MFMA GEMM. R22: 64x128 tiles, grid 512 = 2
// blocks/CU. f32 output path (active for f32 inputs) keeps direct stores.
// ---------------------------------------------------------------------------
__global__ __launch_bounds__(256, 2) void out_gemm(
    const unsigned short* __restrict__ A,
    const unsigned short* __restrict__ Wob, const unsigned short* __restrict__ bob,
    void* __restrict__ out, const int* __restrict__ flag)
{
    const bool f32m = (*flag != 0);
    const int bid = blockIdx.x;            // 512 blocks
    const int r_ = bid & 7, s_ = bid >> 3; // s_ in [0,64)
    const int g = r_ + 8 * (s_ >> 3);      // [0,64) m-tile
    const int m0 = g * 64;
    const int e0 = (s_ & 7) * 128;

    const int tid = threadIdx.x, w = tid >> 6, lane = tid & 63;
    const int quad = lane >> 4, lc = lane & 15;
    const int wx = w & 1, wy = w >> 1;

    __shared__ unsigned short smem[12288];
    #define A_S(c) (&smem[(c) * 2048])
    #define B_S(c) (&smem[4096 + (c) * 4096])

    f4 acc[2][4];
    #pragma unroll
    for (int i = 0; i < 2; i++)
        #pragma unroll
        for (int j = 0; j < 4; j++) acc[i][j] = (f4){0.f, 0.f, 0.f, 0.f};

    const int gr = lane >> 2;
    const int gc = (lane & 3) ^ (gr & 3);
    const size_t aoff = (size_t)(m0 + w*16 + gr) * E_ + gc*8;   // 16 rows/wave
    const size_t boff = (size_t)(e0 + w*32 + gr) * E_ + gc*8;

    glds16(A + aoff, &A_S(0)[(w*64) * 8]);
    #pragma unroll
    for (int j = 0; j < 2; j++)
        glds16(Wob + boff + (size_t)j*16*E_, &B_S(0)[(w*128 + j*64) * 8]);
    __syncthreads();

    const int fcA = quad ^ (lc & 3);
    for (int k0 = 0; k0 < E_; k0 += 32) {
        const int cur = (k0 >> 5) & 1;
        if (k0 + 32 < E_) {
            glds16(A + aoff + k0 + 32, &A_S(cur^1)[(w*64) * 8]);
            #pragma unroll
            for (int j = 0; j < 2; j++)
                glds16(Wob + boff + (size_t)j*16*E_ + k0 + 32, &B_S(cur^1)[(w*128 + j*64) * 8]);
        }
        s8b af[2], bfr[4];
        #pragma unroll
        for (int i = 0; i < 2; i++)
            af[i]  = *(const s8b*)&A_S(cur)[((wy*32 + i*16 + lc)*4 + fcA) * 8];
        #pragma unroll
        for (int i = 0; i < 4; i++)
            bfr[i] = *(const s8b*)&B_S(cur)[((wx*64 + i*16 + lc)*4 + fcA) * 8];
        #pragma unroll
        for (int ms = 0; ms < 2; ms++)
            #pragma unroll
            for (int ns = 0; ns < 4; ns++)
                acc[ms][ns] = MFMA_B16(af[ms], bfr[ns], acc[ms][ns]);
        __syncthreads();
    }

    float bias_v[4];
    #pragma unroll
    for (int ns = 0; ns < 4; ns++) bias_v[ns] = bu2f(bob[e0 + wx*64 + ns*16 + lc]);

    if (f32m) {
        #pragma unroll
        for (int ms = 0; ms < 2; ms++)
            #pragma unroll
            for (int ns = 0; ns < 4; ns++)
                #pragma unroll
                for (int r2 = 0; r2 < 4; r2++) {
                    float val = acc[ms][ns][r2] + bias_v[ns];
                    size_t m = m0 + wy*32 + ms*16 + quad*4 + r2;
                    int e = e0 + wx*64 + ns*16 + lc;
                    ((float*)out)[m * E_ + e] = val;
                }
    } else {
        unsigned int* cst = (unsigned int*)&smem[0];
        __syncthreads();
        #pragma unroll
        for (int ms = 0; ms < 2; ms++)
            #pragma unroll
            for (int ns = 0; ns < 4; ns++)
                #pragma unroll
                for (int r2 = 0; r2 < 4; r2++) {
                    float val = acc[ms][ns][r2] + bias_v[ns];
                    float nb = __shfl_xor(val, 1);
                    if (!(lane & 1)) {
                        int mi = wy*32 + ms*16 + quad*4 + r2;   // 0..63
                        int ei = wx*64 + ns*16 + lc;            // even
                        int col = ei >> 1;                      // 0..63
                        cst[mi*64 + (col ^ ((mi & 7) << 2))] = pk2(val, nb);
                    }
                }
        __syncthreads();
        unsigned int* dst32 = (unsigned int*)out;
        #pragma unroll
        for (int i = 0; i < 4; i++) {
            const int li  = i*256 + tid;              // 0..1023
            const int row = li >> 4;                  // 0..63
            const int ch  = li & 15;                  // 16 chunks x 16B
            uint4 vd = *(const uint4*)&cst[row*64 + ((ch*4) ^ ((row & 7) << 2))];
            const size_t du = ((size_t)(m0 + row) * E_ + e0) / 2 + ch*4;
            *(uint4*)&dst32[du] = vd;
        }
    }
    #undef A_S
    #undef B_S
}

extern "C" void kernel_launch(void* const* d_in, const int* in_sizes, int n_in,
                              void* d_out, int out_size, void* d_ws, size_t ws_size,
                              hipStream_t stream) {
    const void* x  = d_in[0];
    const void* Wq = d_in[1];  const void* bq = d_in[2];
    const void* Wk = d_in[3];  const void* bk = d_in[4];
    const void* Wv = d_in[5];  const void* bv = d_in[6];
    const void* Wo = d_in[7];  const void* bo = d_in[8];
    const void* rk = d_in[9];  const void* rv = d_in[10];

    int* flag = (int*)d_ws;
    const size_t HTD = (size_t)NH_ * T_ * D_;        // 4,194,304 elems
    unsigned short* qw = (unsigned short*)((char*)d_ws + 256);
    unsigned short* kw = qw + HTD;
    unsigned short* vw = kw + HTD;                   // V^T [N][D][T] bf16
    unsigned short* aw = vw + HTD;                   // [4096][1024] bf16 pre-Wo
    unsigned short* xw = aw + (size_t)M_ * E_;       // x as bf16 (8 MB)
    unsigned short* Ww = xw + (size_t)M_ * E_;       // Wq,Wk,Wv,Wo bf16 (8 MB)
    unsigned short* bw = Ww + (size_t)4 * E_ * E_;   // bq,bk,bv,bo bf16 (8 KB)
    // ws use: ~48 MB

    cvt_bf16<<<dim3(4100), 256, 0, stream>>>(
        x, Wq, Wk, Wv, Wo, bq, bk, bv, bo, xw, Ww, bw, flag);
    qkv_gemm<<<dim3(768), 256, 0, stream>>>(xw, Ww, bw, qw, kw, vw);
    attn_mfma<<<dim3(NH_ * (T_/128)), 512, 0, stream>>>(qw, kw, vw, rk, rv, aw, flag);
    out_gemm<<<dim3(512), 256, 0, stream>>>(aw, Ww + (size_t)3*E_*E_, bw + 3*E_,
                                            d_out, flag);
}

// Round 16
// 207.280 us; speedup vs baseline: 2.5635x; 1.0135x over previous
//
#include <hip/hip_runtime.h>
#include <hip/hip_bf16.h>
#include <math.h>

#define T_   2048
#define B_   2
#define E_   1024
#define H_   16
#define D_   64
#define NH_  32
#define M_   4096

typedef __attribute__((ext_vector_type(8))) short s8b;   // 8 bf16 (4 VGPRs)
typedef __attribute__((ext_vector_type(4))) float f4;    // 4 f32 acc
typedef __attribute__((ext_vector_type(16))) float f16v; // 32x32 MFMA acc

#define MFMA_B16(a,b,c) __builtin_amdgcn_mfma_f32_16x16x32_bf16(a,b,c,0,0,0)
#define MFMA32(a,b,c)   __builtin_amdgcn_mfma_f32_32x32x16_bf16(a,b,c,0,0,0)
#define LOG2E 1.44269504088896f

__device__ __forceinline__ unsigned short f2bu(float f) {
    union { __hip_bfloat16 h; unsigned short u; } cv;
    cv.h = __float2bfloat16(f);
    return cv.u;
}
// fast bf16: round-half-up truncation (positive finite values) — 2 VALU ops
__device__ __forceinline__ unsigned short f2bu_fast(float f) {
    return (unsigned short)((__float_as_uint(f) + 0x8000u) >> 16);
}
__device__ __forceinline__ float bu2f(unsigned short u) {
    union { __hip_bfloat16 h; unsigned short u; } cv; cv.u = u;
    return __bfloat162float(cv.h);
}
__device__ __forceinline__ unsigned int pk2(float a, float b) {
    return (unsigned int)f2bu(a) | ((unsigned int)f2bu(b) << 16);
}
// pack two f32 -> packed bf16 pair with round-half-up (cheap)
__device__ __forceinline__ unsigned int pk2_fast(float a, float b) {
    return ((__float_as_uint(a) + 0x8000u) >> 16) |
           ((__float_as_uint(b) + 0x8000u) & 0xFFFF0000u);
}
// raw v_exp_f32 — exp2f() without fast-math expands to a denorm-guard
// sequence (~12 extra VALU ops); attention scores never reach denormals.
__device__ __forceinline__ float fexp2(float x) {
    return __builtin_amdgcn_exp2f(x);
}
__device__ __forceinline__ float ld1d(const void* p, size_t idx, bool f32) {
    return f32 ? ((const float*)p)[idx] : bu2f(((const unsigned short*)p)[idx]);
}
// swap: a' = {a.lo32, b.lo32}, b' = {a.hi32, b.hi32} (v_permlane32_swap_b32)
__device__ __forceinline__ void plswap(unsigned int &a, unsigned int &b) {
    auto r = __builtin_amdgcn_permlane32_swap(a, b, false, false);
    a = r[0]; b = r[1];
}
// async global->LDS, 16 B per lane (GEMMs only — attn uses register prefetch
// because its per-tile barrier drains vmcnt(0) and exposes the DMA latency)
__device__ __forceinline__ void glds16(const unsigned short* g, unsigned short* l) {
    __builtin_amdgcn_global_load_lds(
        (const __attribute__((address_space(1))) unsigned int*)g,
        (__attribute__((address_space(3))) unsigned int*)l, 16, 0, 0);
}
// dtype detect, wave-local (identical result in every wave): sample 64 u16
// words of x; bf16 data -> ~all exponent fields sane; f32-as-u16 -> ~half.
__device__ __forceinline__ bool detect_f32(const unsigned short* q16) {
    int e = (q16[threadIdx.x & 63] >> 7) & 0xFF;
    bool sane = (e == 0) || (e >= 97 && e <= 157);
    unsigned long long m = __ballot(sane);
    return __popcll(m) < 56;   // true = f32 inputs
}

// ---------------------------------------------------------------------------
// One-pass f32->bf16 conversion of x, Wq..Wo, bq..bo into ws. R21: exact 1D
// grid (4100 blocks). Also publishes the dtype flag.
// ---------------------------------------------------------------------------
__global__ __launch_bounds__(256) void cvt_bf16(
    const void* __restrict__ x,
    const void* __restrict__ Wq, const void* __restrict__ Wk,
    const void* __restrict__ Wv, const void* __restrict__ Wo,
    const void* __restrict__ bq, const void* __restrict__ bk,
    const void* __restrict__ bv, const void* __restrict__ bo,
    unsigned short* __restrict__ xw, unsigned short* __restrict__ Ww,
    unsigned short* __restrict__ bw, int* __restrict__ flag)
{
    const bool f32m = detect_f32((const unsigned short*)x);
    const int bid = blockIdx.x;
    if (bid == 0 && threadIdx.x == 0)
        *flag = f32m ? 1 : 0;
    int y, lb;
    if (bid < 2048)       { y = 0;                      lb = bid; }
    else if (bid < 4096)  { y = 1 + ((bid - 2048) >> 9); lb = (bid - 2048) & 511; }
    else                  { y = 5 + (bid - 4096);        lb = 0; }
    const void* src; unsigned short* dst; int n;
    if (y == 0)      { src = x; dst = xw; n = M_ * E_; }
    else if (y <= 4) {
        src = (y == 1) ? Wq : (y == 2) ? Wk : (y == 3) ? Wv : Wo;
        dst = Ww + (size_t)(y - 1) * E_ * E_; n = E_ * E_;
    } else {
        src = (y == 5) ? bq : (y == 6) ? bk : (y == 7) ? bv : bo;
        dst = bw + (size_t)(y - 5) * E_; n = E_;
    }
    int i = (lb * 256 + threadIdx.x) * 8;
    if (i >= n) return;
    if (f32m) {
        const float* s = (const float*)src + i;
        float4 f0 = *(const float4*)s, f1 = *(const float4*)(s + 4);
        union { unsigned int d[4]; s8b v; } u;
        u.d[0] = pk2(f0.x, f0.y); u.d[1] = pk2(f0.z, f0.w);
        u.d[2] = pk2(f1.x, f1.y); u.d[3] = pk2(f1.z, f1.w);
        *(s8b*)(dst + i) = u.v;
    } else {
        *(s8b*)(dst + i) = *(const s8b*)((const unsigned short*)src + i);
    }
}

// ---------------------------------------------------------------------------
// QKV projection, bf16 MFMA GEMM, XCD swizzle, glds staging (xor-swizzled),
// double-buffered single-barrier. p==2 (V) written TRANSPOSED [N][D][T] via
// LDS-staged coalesced stores (R20). R21: Q/K epilogue ALSO LDS-staged.
// ---------------------------------------------------------------------------
__global__ __launch_bounds__(256, 3) void qkv_gemm(
    const unsigned short* __restrict__ xw, const unsigned short* __restrict__ Ww,
    const unsigned short* __restrict__ bw,
    unsigned short* __restrict__ qo, unsigned short* __restrict__ ko,
    unsigned short* __restrict__ vo)
{
    const int bid = blockIdx.x;            // 768 blocks
    const int r_ = bid & 7, s_ = bid >> 3;
    const int g = r_ + 8 * (s_ >> 3);      // group in [0,96): (m,p)
    const int e0 = (s_ & 7) * 128;
    const int m0 = (g & 31) * 128;
    const int p  = g >> 5;
    const unsigned short* W    = Ww + (size_t)p * E_ * E_;
    const unsigned short* bias = bw + (size_t)p * E_;
    const float scale = (p == 0) ? 0.125f * LOG2E : 1.0f;

    const int tid = threadIdx.x, w = tid >> 6, lane = tid & 63;
    const int quad = lane >> 4, lc = lane & 15;
    const int wx = w & 1, wy = w >> 1;

    __shared__ unsigned short smem[4][128 * 32];

    f4 acc[4][4];
    #pragma unroll
    for (int i = 0; i < 4; i++)
        #pragma unroll
        for (int j = 0; j < 4; j++) acc[i][j] = (f4){0.f, 0.f, 0.f, 0.f};

    const int gr = lane >> 2;
    const int gc = (lane & 3) ^ ((lane >> 2) & 3);
    const size_t aoff = (size_t)(m0 + w*32 + gr) * E_ + gc*8;
    const size_t boff = (size_t)(e0 + w*32 + gr) * E_ + gc*8;

    #pragma unroll
    for (int j = 0; j < 2; j++) {
        glds16(xw + aoff + (size_t)j*16*E_, &smem[0][(w*128 + j*64) * 8]);
        glds16(W  + boff + (size_t)j*16*E_, &smem[2][(w*128 + j*64) * 8]);
    }
    __syncthreads();

    const int fcA = quad ^ (lc & 3);
    for (int k0 = 0; k0 < E_; k0 += 32) {
        const int cur = (k0 >> 5) & 1;
        if (k0 + 32 < E_) {
            #pragma unroll
            for (int j = 0; j < 2; j++) {
                glds16(xw + aoff + (size_t)j*16*E_ + k0 + 32, &smem[cur^1][(w*128 + j*64) * 8]);
                glds16(W  + boff + (size_t)j*16*E_ + k0 + 32, &smem[2 + (cur^1)][(w*128 + j*64) * 8]);
            }
        }
        s8b af[4], bfr[4];
        #pragma unroll
        for (int i = 0; i < 4; i++)
            af[i]  = *(const s8b*)&smem[cur][((wy*64 + i*16 + lc)*4 + fcA) * 8];
        #pragma unroll
        for (int i = 0; i < 4; i++)
            bfr[i] = *(const s8b*)&smem[2 + cur][((wx*64 + i*16 + lc)*4 + fcA) * 8];
        #pragma unroll
        for (int ms = 0; ms < 4; ms++)
            #pragma unroll
            for (int ns = 0; ns < 4; ns++)
                acc[ms][ns] = MFMA_B16(af[ms], bfr[ns], acc[ms][ns]);
        __syncthreads();
    }

    float bias_v[4];
    #pragma unroll
    for (int ns = 0; ns < 4; ns++) bias_v[ns] = bu2f(bias[e0 + wx*64 + ns*16 + lc]);

    unsigned int* cst = (unsigned int*)&smem[0][0];   // 8192 u32 = 32 KB
    if (p < 2) {
        // ---- Q/K epilogue, LDS-staged ----
        #pragma unroll
        for (int ms = 0; ms < 4; ms++)
            #pragma unroll
            for (int ns = 0; ns < 4; ns++)
                #pragma unroll
                for (int r2 = 0; r2 < 4; r2++) {
                    float val = (acc[ms][ns][r2] + bias_v[ns]) * scale;
                    float nb = __shfl_xor(val, 1);
                    if (!(lane & 1)) {
                        int mi = wy*64 + ms*16 + quad*4 + r2;     // 0..127
                        int ei = wx*64 + ns*16 + lc;              // 0..127, even
                        int row = ((mi & 1) * 2 + (ei >> 6)) * 64 + (mi >> 1);
                        int col = (ei & 63) >> 1;                 // 0..31
                        cst[row*32 + (col ^ ((row & 7) << 2))] = pk2(val, nb);
                    }
                }
        __syncthreads();
        unsigned int* dst32 = (unsigned int*)((p == 0) ? qo : ko);
        #pragma unroll
        for (int i = 0; i < 8; i++) {
            const int li  = i*256 + tid;              // 0..2047
            const int row = li >> 3;                  // 0..255
            const int ch  = li & 7;                   // 16B chunk
            uint4 vd = *(const uint4*)&cst[row*32 + ((ch*4) ^ ((row & 7) << 2))];
            const int bb = row >> 7, hh = (row >> 6) & 1, tq = row & 63;
            const size_t du = (((size_t)(bb*H_ + (e0 >> 6) + hh) * T_
                                + (m0 >> 1) + tq) << 5) + ch*4;
            *(uint4*)&dst32[du] = vd;
        }
    } else {
        // ---- V epilogue, LDS-staged (R20) ----
        #pragma unroll
        for (int ms = 0; ms < 4; ms++) {
            const int tq = wy*16 + ms*4 + quad;           // [0,32)
            #pragma unroll
            for (int ns = 0; ns < 4; ns++) {
                const int e_l = wx*64 + ns*16 + lc;       // [0,128)
                const int x = (e_l & 7) << 2;
                float v0 = acc[ms][ns][0] + bias_v[ns];
                float v1 = acc[ms][ns][1] + bias_v[ns];
                float v2 = acc[ms][ns][2] + bias_v[ns];
                float v3 = acc[ms][ns][3] + bias_v[ns];
                cst[e_l*64 + ( tq       ^ x)] = pk2(v0, v2);   // bb = 0
                cst[e_l*64 + ((32 + tq) ^ x)] = pk2(v1, v3);   // bb = 1
            }
        }
        __syncthreads();
        #pragma unroll
        for (int i = 0; i < 8; i++) {
            const int li  = i*256 + tid;                  // [0,2048)
            const int e_l = li >> 4;
            const int bb  = (li >> 3) & 1;
            const int ch  = li & 7;                       // 16B chunk
            const int x   = (e_l & 7) << 2;
            uint4 vd = *(const uint4*)&cst[e_l*64 + ((bb*32 + ch*4) ^ x)];
            const int e = e0 + e_l, h = e >> 6, d = e & 63;
            const size_t du = ((size_t)(bb*H_ + h) * 64 + d) * (T_/2)
                              + (m0 >> 2) + ch*4;
            *(uint4*)((unsigned int*)vo + du) = vd;
        }
    }
}

// ---------------------------------------------------------------------------
// Flash attention with Shaw bias — R26 = R23 exactly (best measured attn,
// 70.2us): 32x32x16 MFMA (2x FLOP per LDS operand byte), 8 waves = 4
// t-groups x 2 s-halves, P in registers via permlane32_swap, scalar VALU
// rowsums (VGPR 64, no spill), DIRECT uint2 stores (R25 isolated the
// LDS-staged aout store as -8us: extra barriers + idle sh==1 waves).
// R24 lesson pinned in place: never exceed ~100 VGPR here (4 waves/SIMD
// budget is 128; 3 f16v accumulators = +48 VGPR = scratch spill = 5.6x).
// ---------------------------------------------------------------------------
__global__ __launch_bounds__(512, 4) void attn_mfma(
    const unsigned short* __restrict__ q, const unsigned short* __restrict__ k,
    const unsigned short* __restrict__ v,
    const void* __restrict__ rk_t, const void* __restrict__ rv_t,
    unsigned short* __restrict__ aout, const int* __restrict__ flag)
{
    const bool f32m = (*flag != 0);
    const int bid = blockIdx.x;
    const int n = bid & 31, qt = bid >> 5;
    const int t0 = qt * 128;
    const int tid = threadIdx.x, w = tid >> 6, lane = tid & 63;
    const int quad = lane >> 4, lc = lane & 15;
    const int tg = w >> 1, sh = w & 1;          // t-group, s-half
    const int lh = lane >> 5, tloc = lane & 31; // half-wave, local t (or row)
    const int t_bl = tg * 32 + tloc;            // block-local t of this lane

    __shared__ unsigned short k_s[2][64 * 64];   // K[s][d] swizzled; epi: O-buf/rv^T
    __shared__ unsigned short v_s[2][64 * 64];   // V^T[d][s] swizzled; epi: O-buf
    __shared__ unsigned short p_s[4][32 * 72];   // rk staging / P_extra per t-group
    __shared__ unsigned short qrk_s[128 * 36];   // qrk[t_local][r] bf16 (log2 dom.)
    __shared__ unsigned short diag16[128 * 33];  // e-values at |rel|<16, bf16
    __shared__ float st3[2][3][128];             // per-s-half {l, L, R} per t

    const unsigned short* qn = q + ((size_t)n * T_ + t0) * D_;
    const unsigned short* kn = k + (size_t)n * T_ * D_;
    const unsigned short* vn = v + (size_t)n * D_ * T_;   // V^T [D][T]

    for (int i = tid; i < 128 * 33; i += 512) diag16[i] = 0;

    // stage rk (bf16, padded [48][72], rows>=33 zero) into p_s area
    unsigned int* rks = (unsigned int*)&p_s[0][0];
    for (int i = tid; i < 48 * 36; i += 512) {
        int r = i / 36, c2 = i % 36;
        unsigned int val = 0;
        if (r < 33 && c2 < 32)
            val = pk2(ld1d(rk_t, r*64 + 2*c2, f32m), ld1d(rk_t, r*64 + 2*c2 + 1, f32m));
        rks[i] = val;
    }
    __syncthreads();

    // qrk[t][r] = q[t] . rk[r] via 16x16 MFMA (prologue-only, rows w*16..+15)
    {
        s8b qa16[2];
        #pragma unroll
        for (int kf = 0; kf < 2; kf++)
            qa16[kf] = *(const s8b*)(qn + (size_t)(w*16 + lc) * D_ + kf*32 + quad*8);
        for (int nt = 0; nt < 3; nt++) {
            s8b b0 = *(const s8b*)((const unsigned short*)rks + (nt*16 + lc)*72 + quad*8);
            s8b b1 = *(const s8b*)((const unsigned short*)rks + (nt*16 + lc)*72 + 32 + quad*8);
            f4 a = (f4){0.f, 0.f, 0.f, 0.f};
            a = MFMA_B16(qa16[0], b0, a);
            a = MFMA_B16(qa16[1], b1, a);
            #pragma unroll
            for (int r = 0; r < 4; r++) {
                float nb = __shfl_xor(a[r], 1);
                int col = nt*16 + lc;
                if (!(lane & 1) && col < 34)
                    ((unsigned int*)qrk_s)[(w*16 + quad*4 + r)*18 + (col >> 1)] = pk2(a[r], nb);
            }
        }
    }
    __syncthreads();   // rk staging (aliased with p_s) free after this

    // Q fragments, 32x32 B-operand: B[n=t=lane&31][k=d=16*ks+8*lh+j]
    s8b qa32[4];
    #pragma unroll
    for (int ks = 0; ks < 4; ks++)
        qa32[ks] = *(const s8b*)(qn + (size_t)t_bl * D_ + ks*16 + lh*8);

    const float qLn = bu2f(qrk_s[t_bl*36 + 0]);
    const float qRn = bu2f(qrk_s[t_bl*36 + 32]);
    float L_p = 0.f, R_p = 0.f, sN = 0.f, sL = 0.f, sR = 0.f;
    f16v O[2];
    #pragma unroll
    for (int dt = 0; dt < 2; dt++)
        #pragma unroll
        for (int r = 0; r < 16; r++) O[dt][r] = 0.f;

    // staging: row = w*8 + (lane>>3); phys chunk = lane&7; source chunk
    // gcc = phys ^ (row&7) ^ ((row>>3)&1)  [row&7 = lane>>3, row>>3 = w]
    const int grr = lane >> 3;
    const int gcc = (lane & 7) ^ grr ^ (w & 1);
    const size_t koff = (size_t)(w*8 + grr) * D_ + gcc*8;   // + s0*D_
    const size_t voff = (size_t)(w*8 + grr) * T_ + gcc*8;   // + s0

    // tile-order stagger: co-resident pair (bid, bid+256) -> opposite phase
    const int kts = ((bid >> 8) & 1) * 16;

    s8b kr0 = *(const s8b*)(kn + koff + (size_t)(kts * 64) * D_);
    s8b vr0 = *(const s8b*)(vn + voff + kts * 64);
    *(s8b*)&k_s[0][(w*64 + lane) * 8] = kr0;
    *(s8b*)&v_s[0][(w*64 + lane) * 8] = vr0;
    __syncthreads();

    const int rK   = sh*32 + tloc;                       // K row in k_s
    const int swzK = (rK & 7) ^ ((rK >> 3) & 1);
    for (int it = 0; it < 32; it++) {
        const int kt = (it + kts) & 31;
        const int s0 = kt * 64;
        const int cur = it & 1;
        if (it + 1 < 32) {
            const int s0n = ((it + 1 + kts) & 31) * 64;
            kr0 = *(const s8b*)(kn + koff + (size_t)s0n * D_);
            vr0 = *(const s8b*)(vn + voff + s0n);
        }

        const bool farL  = (s0 + 63 < t0 - 16);
        const bool farR  = (s0 > t0 + 143);
        const bool nearT = !farL && !farR;

        // K fragments, A-operand: A[m=s=rK][k=d=16*ks+8*lh+j]
        s8b ak32[4];
        #pragma unroll
        for (int ks = 0; ks < 4; ks++)
            ak32[ks] = *(const s8b*)&k_s[cur][(rK*8 + ((2*ks + lh) ^ swzK)) * 8];

        f16v S;
        {
            float ini = nearT ? 0.f : (farL ? qLn : qRn);
            #pragma unroll
            for (int r = 0; r < 16; r++) S[r] = ini;
        }
        #pragma unroll
        for (int ks = 0; ks < 4; ks++)
            S = MFMA32(ak32[ks], qa32[ks], S);

        // exp2 (+ Shaw near-diag bias), class sums, in-place e-values
        if (nearT) {
            #pragma unroll
            for (int r = 0; r < 16; r++) {
                int Sl  = (r & 3) + 8*(r >> 2) + 4*lh;         // s-local row
                int rel = s0 + sh*32 + Sl - (t0 + t_bl);
                int rc  = rel < -16 ? -16 : (rel > 16 ? 16 : rel);
                float e = fexp2(S[r] + bu2f(qrk_s[t_bl*36 + rc + 16]));
                S[r] = e;
                if (rel <= -16)      L_p += e;
                else if (rel >= 16)  R_p += e;
                else                 diag16[t_bl*33 + rel + 15] = f2bu_fast(e);
            }
        } else {
            #pragma unroll
            for (int r = 0; r < 16; r++) S[r] = fexp2(S[r]);
        }
        {
            float ss = ((S[0]+S[1])+(S[2]+S[3])) + ((S[4]+S[5])+(S[6]+S[7]))
                     + ((S[8]+S[9])+(S[10]+S[11])) + ((S[12]+S[13])+(S[14]+S[15]));
            if (nearT) sN += ss; else if (farL) sL += ss; else sR += ss;
        }

        // P -> in-register B fragments (k = s-local): pack pairs then swap
        unsigned int wl[8];
        #pragma unroll
        for (int g2 = 0; g2 < 4; g2++) {
            wl[2*g2]   = pk2_fast(S[4*g2],   S[4*g2+1]);
            wl[2*g2+1] = pk2_fast(S[4*g2+2], S[4*g2+3]);
        }
        plswap(wl[0], wl[2]);  plswap(wl[1], wl[3]);
        plswap(wl[4], wl[6]);  plswap(wl[5], wl[7]);
        union { unsigned int d[4]; s8b v; } pb0, pb1;
        pb0.d[0] = wl[0]; pb0.d[1] = wl[1]; pb0.d[2] = wl[2]; pb0.d[3] = wl[3];
        pb1.d[0] = wl[4]; pb1.d[1] = wl[5]; pb1.d[2] = wl[6]; pb1.d[3] = wl[7];

        // O^T += V^T . P^T : A[m=d][k=s], 2 d-tiles x 2 k-slices
        #pragma unroll
        for (int dt = 0; dt < 2; dt++) {
            const int rV   = dt*32 + tloc;
            const int swzV = (rV & 7) ^ ((rV >> 3) & 1);
            s8b av0 = *(const s8b*)&v_s[cur][(rV*8 + ((sh*4 + 0 + lh) ^ swzV)) * 8];
            s8b av1 = *(const s8b*)&v_s[cur][(rV*8 + ((sh*4 + 2 + lh) ^ swzV)) * 8];
            O[dt] = MFMA32(av0, pb0.v, O[dt]);
            O[dt] = MFMA32(av1, pb1.v, O[dt]);
        }

        if (it + 1 < 32) {
            *(s8b*)&k_s[cur ^ 1][(w*64 + lane) * 8] = kr0;
            *(s8b*)&v_s[cur ^ 1][(w*64 + lane) * 8] = vr0;
        }
        __syncthreads();
    }

    // ---- epilogue ----
    // combine lane pairs (t in lanes t and t+32), publish per-s-half sums
    sN += __shfl_xor(sN, 32);  sL += __shfl_xor(sL, 32);  sR += __shfl_xor(sR, 32);
    L_p += __shfl_xor(L_p, 32);  R_p += __shfl_xor(R_p, 32);
    if (lh == 0) {
        st3[sh][0][t_bl] = sN + sL + sR;
        st3[sh][1][t_bl] = sL + L_p;
        st3[sh][2][t_bl] = sR + R_p;
    }
    __syncthreads();

    // O reduction across s-half pairs through dead K/V buffers (f32, swizzled)
    float* obuf = (tg == 0) ? (float*)&k_s[0][0] :
                  (tg == 1) ? (float*)&k_s[1][0] :
                  (tg == 2) ? (float*)&v_s[0][0] : (float*)&v_s[1][0];
    const int xort = (tloc & 7) << 2;
    if (sh == 1) {
        #pragma unroll
        for (int dt = 0; dt < 2; dt++)
            #pragma unroll
            for (int r = 0; r < 16; r++) {
                int Sl = (r & 3) + 8*(r >> 2) + 4*lh;
                obuf[tloc*64 + ((dt*32 + Sl) ^ xort)] = O[dt][r];
            }
    }
    __syncthreads();
    if (sh == 0) {
        #pragma unroll
        for (int dt = 0; dt < 2; dt++)
            #pragma unroll
            for (int r = 0; r < 16; r++) {
                int Sl = (r & 3) + 8*(r >> 2) + 4*lh;
                O[dt][r] += obuf[tloc*64 + ((dt*32 + Sl) ^ xort)];
            }
    }
    __syncthreads();

    // stage rv TRANSPOSED into k_s[0] with the main-loop swizzle (r>=33 zero)
    {
        unsigned int* rvs = (unsigned int*)&k_s[0][0];
        for (int i = tid; i < 64 * 32; i += 512) {
            int d = i >> 5, dwL = i & 31;
            int r0 = dwL * 2, r1 = r0 + 1;
            float x0 = (r0 < 33) ? ld1d(rv_t, (size_t)r0 * 64 + d, f32m) : 0.f;
            float x1 = (r1 < 33) ? ld1d(rv_t, (size_t)r1 * 64 + d, f32m) : 0.f;
            int phys = d * 32 + (((dwL >> 2) ^ (d & 7) ^ ((d >> 3) & 1)) * 4) + (dwL & 3);
            rvs[phys] = pk2(x0, x1);
        }
    }
    // build P_extra[32][64] bf16 per t-group (cols 33..63 = 0)
    for (int j = 0; j < 16; j++) {
        int rloc = (w & 1) * 16 + j;
        int trow = (w >> 1) * 32 + rloc;
        int c = lane;
        unsigned short pv;
        if (c == 0)        pv = f2bu(st3[0][1][trow] + st3[1][1][trow]);
        else if (c == 32)  pv = f2bu(st3[0][2][trow] + st3[1][2][trow]);
        else if (c < 32)   pv = diag16[trow*33 + c - 1];
        else               pv = 0;
        p_s[w >> 1][rloc*72 + c] = pv;
    }
    __syncthreads();

    if (sh == 0) {
        // O^T += rv^T . P_extra^T (32x32): B from p_s[tg], A from k_s[0]
        s8b pe[4];
        #pragma unroll
        for (int ks = 0; ks < 4; ks++)
            pe[ks] = *(const s8b*)&p_s[tg][tloc*72 + ks*16 + lh*8];
        #pragma unroll
        for (int dt = 0; dt < 2; dt++) {
            const int rD   = dt*32 + tloc;
            const int swzD = (rD & 7) ^ ((rD >> 3) & 1);
            #pragma unroll
            for (int ks = 0; ks < 4; ks++) {
                s8b ar = *(const s8b*)&k_s[0][(rD*8 + ((2*ks + lh) ^ swzD)) * 8];
                O[dt] = MFMA32(ar, pe[ks], O[dt]);
            }
        }
        // normalize + store bf16 [T][B][E] — packed 8B stores
        const int bb = n >> 4, hh = n & 15;
        const float linv = 1.f / (st3[0][0][t_bl] + st3[1][0][t_bl]);
        const int t_g = t0 + t_bl;
        #pragma unroll
        for (int dt = 0; dt < 2; dt++)
            #pragma unroll
            for (int g2 = 0; g2 < 4; g2++) {
                float v0 = O[dt][4*g2]   * linv;
                float v1 = O[dt][4*g2+1] * linv;
                float v2 = O[dt][4*g2+2] * linv;
                float v3 = O[dt][4*g2+3] * linv;
                int e = hh*64 + dt*32 + 8*g2 + 4*lh;
                *(uint2*)&aout[((size_t)t_g * B_ + bb) * E_ + e] =
                    make_uint2(pk2(v0, v1), pk2(v2, v3));
            }
    }
}

// ---------------------------------------------------------------------------
// Output projection, bf16 MFMA GEMM. R22: 64x128 tiles, grid 512 = 2
// blocks/CU. f32 output path (active for f32 inputs) keeps direct stores.
// ---------------------------------------------------------------------------
__global__ __launch_bounds__(256, 2) void out_gemm(
    const unsigned short* __restrict__ A,
    const unsigned short* __restrict__ Wob, const unsigned short* __restrict__ bob,
    void* __restrict__ out, const int* __restrict__ flag)
{
    const bool f32m = (*flag != 0);
    const int bid = blockIdx.x;            // 512 blocks
    const int r_ = bid & 7, s_ = bid >> 3; // s_ in [0,64)
    const int g = r_ + 8 * (s_ >> 3);      // [0,64) m-tile
    const int m0 = g * 64;
    const int e0 = (s_ & 7) * 128;

    const int tid = threadIdx.x, w = tid >> 6, lane = tid & 63;
    const int quad = lane >> 4, lc = lane & 15;
    const int wx = w & 1, wy = w >> 1;

    __shared__ unsigned short smem[12288];
    #define A_S(c) (&smem[(c) * 2048])
    #define B_S(c) (&smem[4096 + (c) * 4096])

    f4 acc[2][4];
    #pragma unroll
    for (int i = 0; i < 2; i++)
        #pragma unroll
        for (int j = 0; j < 4; j++) acc[i][j] = (f4){0.f, 0.f, 0.f, 0.f};

    const int gr = lane >> 2;
    const int gc = (lane & 3) ^ (gr & 3);
    const size_t aoff = (size_t)(m0 + w*16 + gr) * E_ + gc*8;   // 16 rows/wave
    const size_t boff = (size_t)(e0 + w*32 + gr) * E_ + gc*8;

    glds16(A + aoff, &A_S(0)[(w*64) * 8]);
    #pragma unroll
    for (int j = 0; j < 2; j++)
        glds16(Wob + boff + (size_t)j*16*E_, &B_S(0)[(w*128 + j*64) * 8]);
    __syncthreads();

    const int fcA = quad ^ (lc & 3);
    for (int k0 = 0; k0 < E_; k0 += 32) {
        const int cur = (k0 >> 5) & 1;
        if (k0 + 32 < E_) {
            glds16(A + aoff + k0 + 32, &A_S(cur^1)[(w*64) * 8]);
            #pragma unroll
            for (int j = 0; j < 2; j++)
                glds16(Wob + boff + (size_t)j*16*E_ + k0 + 32, &B_S(cur^1)[(w*128 + j*64) * 8]);
        }
        s8b af[2], bfr[4];
        #pragma unroll
        for (int i = 0; i < 2; i++)
            af[i]  = *(const s8b*)&A_S(cur)[((wy*32 + i*16 + lc)*4 + fcA) * 8];
        #pragma unroll
        for (int i = 0; i < 4; i++)
            bfr[i] = *(const s8b*)&B_S(cur)[((wx*64 + i*16 + lc)*4 + fcA) * 8];
        #pragma unroll
        for (int ms = 0; ms < 2; ms++)
            #pragma unroll
            for (int ns = 0; ns < 4; ns++)
                acc[ms][ns] = MFMA_B16(af[ms], bfr[ns], acc[ms][ns]);
        __syncthreads();
    }

    float bias_v[4];
    #pragma unroll
    for (int ns = 0; ns < 4; ns++) bias_v[ns] = bu2f(bob[e0 + wx*64 + ns*16 + lc]);

    if (f32m) {
        #pragma unroll
        for (int ms = 0; ms < 2; ms++)
            #pragma unroll
            for (int ns = 0; ns < 4; ns++)
                #pragma unroll
                for (int r2 = 0; r2 < 4; r2++) {
                    float val = acc[ms][ns][r2] + bias_v[ns];
                    size_t m = m0 + wy*32 + ms*16 + quad*4 + r2;
                    int e = e0 + wx*64 + ns*16 + lc;
                    ((float*)out)[m * E_ + e] = val;
                }
    } else {
        unsigned int* cst = (unsigned int*)&smem[0];
        __syncthreads();
        #pragma unroll
        for (int ms = 0; ms < 2; ms++)
            #pragma unroll
            for (int ns = 0; ns < 4; ns++)
                #pragma unroll
                for (int r2 = 0; r2 < 4; r2++) {
                    float val = acc[ms][ns][r2] + bias_v[ns];
                    float nb = __shfl_xor(val, 1);
                    if (!(lane & 1)) {
                        int mi = wy*32 + ms*16 + quad*4 + r2;   // 0..63
                        int ei = wx*64 + ns*16 + lc;            // even
                        int col = ei >> 1;                      // 0..63
                        cst[mi*64 + (col ^ ((mi & 7) << 2))] = pk2(val, nb);
                    }
                }
        __syncthreads();
        unsigned int* dst32 = (unsigned int*)out;
        #pragma unroll
        for (int i = 0; i < 4; i++) {
            const int li  = i*256 + tid;              // 0..1023
            const int row = li >> 4;                  // 0..63
            const int ch  = li & 15;                  // 16 chunks x 16B
            uint4 vd = *(const uint4*)&cst[row*64 + ((ch*4) ^ ((row & 7) << 2))];
            const size_t du = ((size_t)(m0 + row) * E_ + e0) / 2 + ch*4;
            *(uint4*)&dst32[du] = vd;
        }
    }
    #undef A_S
    #undef B_S
}

extern "C" void kernel_launch(void* const* d_in, const int* in_sizes, int n_in,
                              void* d_out, int out_size, void* d_ws, size_t ws_size,
                              hipStream_t stream) {
    const void* x  = d_in[0];
    const void* Wq = d_in[1];  const void* bq = d_in[2];
    const void* Wk = d_in[3];  const void* bk = d_in[4];
    const void* Wv = d_in[5];  const void* bv = d_in[6];
    const void* Wo = d_in[7];  const void* bo = d_in[8];
    const void* rk = d_in[9];  const void* rv = d_in[10];

    int* flag = (int*)d_ws;
    const size_t HTD = (size_t)NH_ * T_ * D_;        // 4,194,304 elems
    unsigned short* qw = (unsigned short*)((char*)d_ws + 256);
    unsigned short* kw = qw + HTD;
    unsigned short* vw = kw + HTD;                   // V^T [N][D][T] bf16
    unsigned short* aw = vw + HTD;                   // [4096][1024] bf16 pre-Wo
    unsigned short* xw = aw + (size_t)M_ * E_;       // x as bf16 (8 MB)
    unsigned short* Ww = xw + (size_t)M_ * E_;       // Wq,Wk,Wv,Wo bf16 (8 MB)
    unsigned short* bw = Ww + (size_t)4 * E_ * E_;   // bq,bk,bv,bo bf16 (8 KB)
    // ws use: ~48 MB

    cvt_bf16<<<dim3(4100), 256, 0, stream>>>(
        x, Wq, Wk, Wv, Wo, bq, bk, bv, bo, xw, Ww, bw, flag);
    qkv_gemm<<<dim3(768), 256, 0, stream>>>(xw, Ww, bw, qw, kw, vw);
    attn_mfma<<<dim3(NH_ * (T_/128)), 512, 0, stream>>>(qw, kw, vw, rk, rv, aw, flag);
    out_gemm<<<dim3(512), 256, 0, stream>>>(aw, Ww + (size_t)3*E_*E_, bw + 3*E_,
                                            d_out, flag);
}